// Round 11
// baseline (340.218 us; speedup 1.0000x reference)
//
#include <hip/hip_runtime.h>
#include <cstdint>
#include <cstddef>

#define S_LEN 2048
#define D_MODEL 1024
#define HD 64

typedef __attribute__((ext_vector_type(8))) __bf16 bf16x8;
typedef __attribute__((ext_vector_type(8))) unsigned short u16x8;
typedef __attribute__((ext_vector_type(4))) float f32x4;
typedef __attribute__((ext_vector_type(4))) unsigned short u16x4;

static __device__ __forceinline__ unsigned short f32_bf16(float f) {
    unsigned int u = __float_as_uint(f);
    u += 0x7fffu + ((u >> 16) & 1u);
    return (unsigned short)(u >> 16);
}

// native RNE cast: compiler emits v_cvt_pk_bf16_f32 for pairs (1 inst / 2 elems)
static __device__ __forceinline__ unsigned short f32_bf16_rn(float f) {
    return __builtin_bit_cast(unsigned short, (__bf16)f);
}

static __device__ __forceinline__ float fast_exp2(float x) {
#if __has_builtin(__builtin_amdgcn_exp2f)
    return __builtin_amdgcn_exp2f(x);
#else
    float r; asm("v_exp_f32 %0, %1" : "=v"(r) : "v"(x)); return r;
#endif
}

static __device__ __forceinline__ void gload_lds16(const void* g, void* l) {
    __builtin_amdgcn_global_load_lds(
        (const __attribute__((address_space(1))) unsigned int*)g,
        (__attribute__((address_space(3))) unsigned int*)l,
        16, 0, 0);
}

static __device__ __forceinline__ bf16x8 frag8(const unsigned short* p) {
    return __builtin_bit_cast(bf16x8, *(const u16x8*)p);
}

// ---------------- fused prep: x cvt + both weight transposes ----------------
__global__ void prep_k(const float* __restrict__ x, unsigned short* __restrict__ xb,
                       const float* __restrict__ caw, unsigned short* __restrict__ wqt,
                       const float* __restrict__ cpw, unsigned short* __restrict__ wpt)
{
    __shared__ float tile[32][33];
    const int blk = blockIdx.x;
    const int tid = threadIdx.x;
    if (blk < 8192) {
        int i = blk * 256 + tid;                  // exactly 2097152 f32x4
        f32x4 v = ((const f32x4*)x)[i];
        u16x4 o;
        o[0] = f32_bf16(v[0]); o[1] = f32_bf16(v[1]);
        o[2] = f32_bf16(v[2]); o[3] = f32_bf16(v[3]);
        ((u16x4*)xb)[i] = o;
        return;
    }
    const float* in; unsigned short* out; int R, C, bx, by;
    if (blk < 11264) {
        int t = blk - 8192; in = caw; out = wqt; R = 1024; C = 3072;
        bx = t % 96; by = t / 96;
    } else {
        int t = blk - 11264; in = cpw; out = wpt; R = 1024; C = 1024;
        bx = t & 31; by = t >> 5;
    }
    int tx = tid & 31, ty = tid >> 5;
    int x0 = bx * 32, y0 = by * 32;
#pragma unroll
    for (int p = 0; p < 32; p += 8)
        tile[ty + p][tx] = in[(size_t)(y0 + ty + p) * C + x0 + tx];
    __syncthreads();
#pragma unroll
    for (int p = 0; p < 32; p += 8)
        out[(size_t)(x0 + ty + p) * R + y0 + tx] = f32_bf16(tile[tx][ty + p]);
}

// ---------------- shared 128x128 NT bf16 GEMM mainloop (BK=64) ----------------
__device__ __forceinline__ void gemm128_mainloop(
    const unsigned short* __restrict__ A,
    const unsigned short* __restrict__ Bt,
    unsigned short* As, unsigned short* Bs,
    int m0, int n0, int Kdim, f32x4 acc[][4])
{
    const int tid = threadIdx.x;
    const int lane = tid & 63, wave = tid >> 6;
    const int wm = wave & 1, wn = wave >> 1;
    const int quad = lane >> 4, l15 = lane & 15;
    const int srow = wave * 8 + (lane >> 3);
    const int scol = ((lane & 7) ^ (lane >> 3)) * 8;   // swizzled chunk fetch
    const unsigned short* Ag = A + (size_t)(m0 + srow) * Kdim + scol;
    const unsigned short* Bg = Bt + (size_t)(n0 + srow) * Kdim + scol;
    unsigned short* Asw = As + (wave * 8) * 64 + lane * 8;
    unsigned short* Bsw = Bs + (wave * 8) * 64 + lane * 8;
    const int mkey = l15 & 7;

    for (int k0 = 0; k0 < Kdim; k0 += 64) {
        __syncthreads();
#pragma unroll
        for (int p = 0; p < 4; ++p)
            gload_lds16(Ag + (size_t)(p * 32) * Kdim + k0, Asw + (p * 32) * 64);
#pragma unroll
        for (int p = 0; p < 4; ++p)
            gload_lds16(Bg + (size_t)(p * 32) * Kdim + k0, Bsw + (p * 32) * 64);
        __syncthreads();
#pragma unroll
        for (int kh = 0; kh < 2; ++kh) {
            bf16x8 af[4], bfv[4];
#pragma unroll
            for (int i = 0; i < 4; ++i)
                af[i] = frag8(As + (wm * 64 + i * 16 + l15) * 64 +
                              ((((kh << 2) + quad) ^ mkey) << 3));
#pragma unroll
            for (int j = 0; j < 4; ++j)
                bfv[j] = frag8(Bs + (wn * 64 + j * 16 + l15) * 64 +
                               ((((kh << 2) + quad) ^ mkey) << 3));
#pragma unroll
            for (int i = 0; i < 4; ++i)
#pragma unroll
                for (int j = 0; j < 4; ++j)
                    acc[i][j] = __builtin_amdgcn_mfma_f32_16x16x32_bf16(
                        af[i], bfv[j], acc[i][j], 0, 0, 0);
        }
    }
}

// ---------------- QKV GEMM ----------------
__global__ __launch_bounds__(256, 2) void gemm_qkv_k(
    const unsigned short* __restrict__ xb,
    const unsigned short* __restrict__ wt,
    const float* __restrict__ bias,
    unsigned short* __restrict__ q,
    unsigned short* __restrict__ k2,
    unsigned short* __restrict__ vt)
{
    __shared__ unsigned short Sh[128 * 132];   // mainloop uses first 32 KB
    unsigned short* As = Sh;
    unsigned short* Bs = Sh + 128 * 64;
    const int lin = blockIdx.x + 24 * blockIdx.y;        // grid 24x64 = 1536
    const int swz = (lin & 7) * 192 + (lin >> 3);        // bijective chunked
    const int n0 = (swz % 24) * 128, m0 = (swz / 24) * 128;
    f32x4 acc[4][4] = {};
    gemm128_mainloop(xb, wt, As, Bs, m0, n0, 1024, acc);

    const int tid = threadIdx.x;
    const int lane = tid & 63, wave = tid >> 6;
    const int wm = wave & 1, wn = wave >> 1;
    const int quad = lane >> 4, l15 = lane & 15;
    const bool isq = (n0 < 1024);
    const bool isv = (n0 >= 2048);
    const int cb = n0 & 1023;

    if (!isv) {
        unsigned short* outp = isq ? q : k2;
#pragma unroll
        for (int j = 0; j < 4; ++j) {
            int ct = cb + wn * 64 + j * 16 + l15;
            int h = ct >> 6, d = ct & 63;
            float bv = bias[n0 + wn * 64 + j * 16 + l15];
#pragma unroll
            for (int i = 0; i < 4; ++i)
#pragma unroll
                for (int r = 0; r < 4; ++r) {
                    int row = m0 + wm * 64 + i * 16 + quad * 4 + r;
                    int bb = row >> 11, s = row & 2047;
                    float val = acc[i][j][r] + bv;
                    if (isq) val *= 0.1803368801111244f;   // (1/8)*log2(e)
                    outp[((size_t)(bb * 16 + h) * S_LEN + s) * HD + d] = f32_bf16(val);
                }
        }
    } else {
        // ---- V: write transposed [bh][d][s] via LDS (stride 132, bank-clean)
        __syncthreads();   // all waves done with As/Bs fragment reads
#pragma unroll
        for (int j = 0; j < 4; ++j) {
            float bv = bias[n0 + wn * 64 + j * 16 + l15];
            int lc = wn * 64 + j * 16 + l15;
#pragma unroll
            for (int i = 0; i < 4; ++i)
#pragma unroll
                for (int r = 0; r < 4; ++r) {
                    int lr = wm * 64 + i * 16 + quad * 4 + r;
                    Sh[lr * 132 + lc] = f32_bf16(acc[i][j][r] + bv);
                }
        }
        __syncthreads();
        const int lc = (tid & 63) + (wave & 1) * 64;     // 0..127
        const int sh2 = wave >> 1;                       // 0..1
        const int bb = m0 >> 11;
        const int s0 = (m0 & 2047) + sh2 * 64;
        const int bh = bb * 16 + (cb >> 6) + (lc >> 6);
        unsigned short* vp = vt + ((size_t)bh * HD + (lc & 63)) * S_LEN + s0;
#pragma unroll
        for (int k8 = 0; k8 < 8; ++k8) {
            u16x8 w;
#pragma unroll
            for (int e = 0; e < 8; ++e)
                w[e] = Sh[(sh2 * 64 + k8 * 8 + e) * 132 + lc];
            *(u16x8*)(vp + k8 * 8) = w;
        }
    }
}

// ---------------- proj GEMM -> f32 out ----------------
__global__ __launch_bounds__(256, 2) void gemm_proj_k(
    const unsigned short* __restrict__ am,
    const unsigned short* __restrict__ wpt,
    const float* __restrict__ bias,
    float* __restrict__ out)
{
    __shared__ unsigned short As[128 * 64], Bs[128 * 64];
    const int lin = blockIdx.x + 8 * blockIdx.y;         // grid 8x64 = 512
    const int swz = (lin & 7) * 64 + (lin >> 3);         // bijective chunked
    const int n0 = (swz % 8) * 128, m0 = (swz / 8) * 128;
    f32x4 acc[4][4] = {};
    gemm128_mainloop(am, wpt, As, Bs, m0, n0, 1024, acc);

    const int lane = threadIdx.x & 63, wave = threadIdx.x >> 6;
    const int wm = wave & 1, wn = wave >> 1;
    const int quad = lane >> 4, l15 = lane & 15;
#pragma unroll
    for (int j = 0; j < 4; ++j) {
        int col = n0 + wn * 64 + j * 16 + l15;
        float bv = bias[col];
#pragma unroll
        for (int i = 0; i < 4; ++i)
#pragma unroll
            for (int r = 0; r < 4; ++r) {
                int row = m0 + wm * 64 + i * 16 + quad * 4 + r;
                out[(size_t)row * 1024 + col] = acc[i][j][r] + bv;
            }
    }
}

// ---------------- flash attention v11: 1024 blocks, 4 blocks/CU -------------
// v11 = v10 with V-staging dropped (vb direct from global; bh-major XCD map
//   makes the head's Vt L2-resident: 8 heads x 512 KB = 4 MB/XCD = L2 size;
//   ~200cy L2 hits hidden by 16 waves/CU). LDS 34.8 KB (Ps + K dbuf) -> 4
//   blocks/CU at launch_bounds(256,4); VGPR was 80 at (256,3), fits the
//   128 budget. K stays LDS-staged (4-wave broadcast reuse, v6's win).
//   Staging per iter halves -> shorter barrier vmcnt drain.
#define PSTR 72
__global__ __launch_bounds__(256, 4) void flash_attn_k(
    const unsigned short* __restrict__ Q,
    const unsigned short* __restrict__ K,
    const unsigned short* __restrict__ Vt,
    unsigned short* __restrict__ Am)
{
    __shared__ unsigned short Ps[4 * 32 * PSTR];    // 18 KB
    __shared__ unsigned short Ks[2][64 * 64];       // 16 KB (dbuf)

    // bid -> (xcd, qt desc, bh): 128 blocks per XCD = 8 bh x 16 qt,
    // qt-major so long blocks dispatch first.
    const int bid = blockIdx.x;        // 1024 blocks
    const int xcd = bid & 7;
    const int w = bid >> 3;            // 0..127
    const int qt = 15 - (w >> 3);      // 15,15,..(x8),14,.. long-first
    const int bh = xcd * 8 + (w & 7);
    const int b = bh >> 4, h = bh & 15;
    const int tid = threadIdx.x;
    const int lane = tid & 63, wave = tid >> 6;
    const int quad = lane >> 4, l15 = lane & 15;

    const size_t bh_off = (size_t)bh * S_LEN * HD;
    const unsigned short* Kg = K + bh_off;
    const unsigned short* Vtg = Vt + (size_t)bh * HD * S_LEN;

    const int lrow = (lane >> 3) & 7;
    const int scol = ((lane & 7) ^ lrow) * 8;        // pre-swizzled source chunk
    const int srow = wave * 8 + lrow;
    const int ldst = (wave * 8) * 64 + lane * 8;     // linear LDS dest

    const int q_base = qt * 128 + wave * 32;

    // Q A-fragments, direct from global
    bf16x8 qa[2][2];
#pragma unroll
    for (int i = 0; i < 2; ++i)
#pragma unroll
        for (int kk = 0; kk < 2; ++kk)
            qa[i][kk] = frag8(Q + bh_off +
                (size_t)(q_base + i * 16 + l15) * HD + kk * 32 + quad * 8);

    f32x4 oacc[2][4] = {};
    f32x4 lacc[2] = {};
    u16x8 ones_u = {0x3F80, 0x3F80, 0x3F80, 0x3F80, 0x3F80, 0x3F80, 0x3F80, 0x3F80};
    bf16x8 vone = __builtin_bit_cast(bf16x8, ones_u);

    const int nst = 2 * qt + 2;              // uniform staging trip count
    const int nst_w = nst - ((wave < 2) ? 1 : 0);   // last tile fully masked
    unsigned short* pw = Ps + wave * (32 * PSTR);
    const int pkey = (l15 >> 2) & 3;
    const int kvkey = l15 & 7;

    // prologue: stage K tile 0 into buffer 0
#pragma unroll
    for (int pp = 0; pp < 2; ++pp)
        gload_lds16(Kg + (size_t)(srow + pp * 32) * HD + scol,
                    &Ks[0][ldst + (pp * 32) * 64]);
    __syncthreads();

    int cur = 0;
    for (int st = 0; st < nst; ++st) {
        if (st + 1 < nst) {
            const int nx = cur ^ 1;
            const size_t kroff = (size_t)((st + 1) * 64);
#pragma unroll
            for (int pp = 0; pp < 2; ++pp)
                gload_lds16(Kg + (kroff + srow + pp * 32) * HD + scol,
                            &Ks[nx][ldst + (pp * 32) * 64]);
        }
        const unsigned short* ksc = &Ks[cur][0];
        const unsigned short* vp = Vtg + st * 64;

        if (st < nst_w) {
            // S' = (Q*scale) K^T, K fragments from LDS
            f32x4 sacc[2][4] = {};
            __builtin_amdgcn_s_setprio(1);
#pragma unroll
            for (int kk = 0; kk < 2; ++kk) {
                bf16x8 kb[4];
#pragma unroll
                for (int j = 0; j < 4; ++j)
                    kb[j] = frag8(ksc + (j * 16 + l15) * 64 +
                                  ((((kk << 2) + quad) ^ kvkey) << 3));
#pragma unroll
                for (int i = 0; i < 2; ++i)
#pragma unroll
                    for (int j = 0; j < 4; ++j)
                        sacc[i][j] = __builtin_amdgcn_mfma_f32_16x16x32_bf16(
                            qa[i][kk], kb[j], sacc[i][j], 0, 0, 0);
            }
            __builtin_amdgcn_s_setprio(0);

            // causal mask (diagonal-crossing tiles only)
            if (st * 64 + 63 > q_base) {
#pragma unroll
                for (int i = 0; i < 2; ++i)
#pragma unroll
                    for (int j = 0; j < 4; ++j)
#pragma unroll
                        for (int r = 0; r < 4; ++r) {
                            int kg = st * 64 + j * 16 + l15;
                            int qg = q_base + i * 16 + quad * 4 + r;
                            if (kg > qg) sacc[i][j][r] = -__builtin_inff();
                        }
            }

            // P = exp2(s') -> bf16 (native RNE, compiler-packed) -> LDS
#pragma unroll
            for (int i = 0; i < 2; ++i)
#pragma unroll
                for (int j = 0; j < 4; ++j) {
                    int cs = ((j ^ quad) << 4) + l15;
#pragma unroll
                    for (int r = 0; r < 4; ++r)
                        pw[(i * 16 + quad * 4 + r) * PSTR + cs] =
                            f32_bf16_rn(fast_exp2(sacc[i][j][r]));
                }

            // O += P @ V ; l += P @ 1   (V fragments direct from global/L2)
#pragma unroll
            for (int kk = 0; kk < 2; ++kk) {
                bf16x8 vb[4];
#pragma unroll
                for (int d4 = 0; d4 < 4; ++d4)
                    vb[d4] = frag8(vp + (size_t)(d4 * 16 + l15) * S_LEN + kk * 32 + quad * 8);
                const int coff = ((((kk << 1) + (quad >> 1)) ^ pkey) << 4) + ((quad & 1) << 3);

                bf16x8 pa[2];
#pragma unroll
                for (int i = 0; i < 2; ++i)
                    pa[i] = frag8(pw + (i * 16 + l15) * PSTR + coff);
                __builtin_amdgcn_s_setprio(1);
#pragma unroll
                for (int d4 = 0; d4 < 4; ++d4)
#pragma unroll
                    for (int i = 0; i < 2; ++i)
                        oacc[i][d4] = __builtin_amdgcn_mfma_f32_16x16x32_bf16(
                            pa[i], vb[d4], oacc[i][d4], 0, 0, 0);
#pragma unroll
                for (int i = 0; i < 2; ++i)
                    lacc[i] = __builtin_amdgcn_mfma_f32_16x16x32_bf16(
                        pa[i], vone, lacc[i], 0, 0, 0);
                __builtin_amdgcn_s_setprio(0);
            }
        }

        // handoff: all waves done reading Ks[cur]; staging of Ks[cur^1]
        // drained by the barrier's implicit vmcnt(0)
        __syncthreads();
        cur ^= 1;
    }

    // epilogue: O / l -> merged-head bf16 [B*S][1024]
    unsigned short* Amp = Am + ((size_t)(b * S_LEN + q_base)) * D_MODEL + h * 64;
#pragma unroll
    for (int i = 0; i < 2; ++i)
#pragma unroll
        for (int r = 0; r < 4; ++r) {
            float inv = 1.f / lacc[i][r];
            int qloc = i * 16 + quad * 4 + r;
#pragma unroll
            for (int d4 = 0; d4 < 4; ++d4)
                Amp[(size_t)qloc * D_MODEL + d4 * 16 + l15] =
                    f32_bf16_rn(oacc[i][d4][r] * inv);
        }
}

// ---------------- launcher ----------------
extern "C" void kernel_launch(void* const* d_in, const int* in_sizes, int n_in,
                              void* d_out, int out_size, void* d_ws, size_t ws_size,
                              hipStream_t stream)
{
    const float* x = (const float*)d_in[0];
    const float* c_attn_w = (const float*)d_in[1];
    const float* c_attn_b = (const float*)d_in[2];
    const float* c_proj_w = (const float*)d_in[3];
    const float* c_proj_b = (const float*)d_in[4];
    float* out = (float*)d_out;

    char* ws = (char*)d_ws;
    unsigned short* xb  = (unsigned short*)(ws);              // 16 MB; reused as Am
    unsigned short* q   = (unsigned short*)(ws + 16777216);   // 16 MB
    unsigned short* k   = (unsigned short*)(ws + 33554432);   // 16 MB
    unsigned short* vt  = (unsigned short*)(ws + 67108864);   // 16 MB
    unsigned short* wqt = (unsigned short*)(ws + 83886080);   // 6 MB
    unsigned short* wpt = (unsigned short*)(ws + 90177536);   // 2 MB

    prep_k<<<12288, 256, 0, stream>>>(x, xb, c_attn_w, wqt, c_proj_w, wpt);
    gemm_qkv_k<<<dim3(24, 64), 256, 0, stream>>>(xb, wqt, c_attn_b, q, k, vt);
    flash_attn_k<<<1024, 256, 0, stream>>>(q, k, vt, xb /*Am*/);
    gemm_proj_k<<<dim3(8, 64), 256, 0, stream>>>(xb /*Am*/, wpt, c_proj_b, out);
}

// Round 12
// 277.331 us; speedup vs baseline: 1.2268x; 1.2268x over previous
//
#include <hip/hip_runtime.h>
#include <cstdint>
#include <cstddef>

#define S_LEN 2048
#define D_MODEL 1024
#define HD 64

typedef __attribute__((ext_vector_type(8))) __bf16 bf16x8;
typedef __attribute__((ext_vector_type(8))) unsigned short u16x8;
typedef __attribute__((ext_vector_type(4))) float f32x4;
typedef __attribute__((ext_vector_type(4))) unsigned short u16x4;

static __device__ __forceinline__ unsigned short f32_bf16(float f) {
    unsigned int u = __float_as_uint(f);
    u += 0x7fffu + ((u >> 16) & 1u);
    return (unsigned short)(u >> 16);
}

// native RNE cast: compiler emits v_cvt_pk_bf16_f32 for pairs (1 inst / 2 elems)
static __device__ __forceinline__ unsigned short f32_bf16_rn(float f) {
    return __builtin_bit_cast(unsigned short, (__bf16)f);
}

static __device__ __forceinline__ float fast_exp2(float x) {
#if __has_builtin(__builtin_amdgcn_exp2f)
    return __builtin_amdgcn_exp2f(x);
#else
    float r; asm("v_exp_f32 %0, %1" : "=v"(r) : "v"(x)); return r;
#endif
}

static __device__ __forceinline__ void gload_lds16(const void* g, void* l) {
    __builtin_amdgcn_global_load_lds(
        (const __attribute__((address_space(1))) unsigned int*)g,
        (__attribute__((address_space(3))) unsigned int*)l,
        16, 0, 0);
}

static __device__ __forceinline__ bf16x8 frag8(const unsigned short* p) {
    return __builtin_bit_cast(bf16x8, *(const u16x8*)p);
}

// ---------------- fused prep: x cvt + both weight transposes ----------------
__global__ void prep_k(const float* __restrict__ x, unsigned short* __restrict__ xb,
                       const float* __restrict__ caw, unsigned short* __restrict__ wqt,
                       const float* __restrict__ cpw, unsigned short* __restrict__ wpt)
{
    __shared__ float tile[32][33];
    const int blk = blockIdx.x;
    const int tid = threadIdx.x;
    if (blk < 8192) {
        int i = blk * 256 + tid;                  // exactly 2097152 f32x4
        f32x4 v = ((const f32x4*)x)[i];
        u16x4 o;
        o[0] = f32_bf16(v[0]); o[1] = f32_bf16(v[1]);
        o[2] = f32_bf16(v[2]); o[3] = f32_bf16(v[3]);
        ((u16x4*)xb)[i] = o;
        return;
    }
    const float* in; unsigned short* out; int R, C, bx, by;
    if (blk < 11264) {
        int t = blk - 8192; in = caw; out = wqt; R = 1024; C = 3072;
        bx = t % 96; by = t / 96;
    } else {
        int t = blk - 11264; in = cpw; out = wpt; R = 1024; C = 1024;
        bx = t & 31; by = t >> 5;
    }
    int tx = tid & 31, ty = tid >> 5;
    int x0 = bx * 32, y0 = by * 32;
#pragma unroll
    for (int p = 0; p < 32; p += 8)
        tile[ty + p][tx] = in[(size_t)(y0 + ty + p) * C + x0 + tx];
    __syncthreads();
#pragma unroll
    for (int p = 0; p < 32; p += 8)
        out[(size_t)(x0 + ty + p) * R + y0 + tx] = f32_bf16(tile[tx][ty + p]);
}

// ---------------- shared 128x128 NT bf16 GEMM mainloop (BK=64) ----------------
__device__ __forceinline__ void gemm128_mainloop(
    const unsigned short* __restrict__ A,
    const unsigned short* __restrict__ Bt,
    unsigned short* As, unsigned short* Bs,
    int m0, int n0, int Kdim, f32x4 acc[][4])
{
    const int tid = threadIdx.x;
    const int lane = tid & 63, wave = tid >> 6;
    const int wm = wave & 1, wn = wave >> 1;
    const int quad = lane >> 4, l15 = lane & 15;
    const int srow = wave * 8 + (lane >> 3);
    const int scol = ((lane & 7) ^ (lane >> 3)) * 8;   // swizzled chunk fetch
    const unsigned short* Ag = A + (size_t)(m0 + srow) * Kdim + scol;
    const unsigned short* Bg = Bt + (size_t)(n0 + srow) * Kdim + scol;
    unsigned short* Asw = As + (wave * 8) * 64 + lane * 8;
    unsigned short* Bsw = Bs + (wave * 8) * 64 + lane * 8;
    const int mkey = l15 & 7;

    for (int k0 = 0; k0 < Kdim; k0 += 64) {
        __syncthreads();
#pragma unroll
        for (int p = 0; p < 4; ++p)
            gload_lds16(Ag + (size_t)(p * 32) * Kdim + k0, Asw + (p * 32) * 64);
#pragma unroll
        for (int p = 0; p < 4; ++p)
            gload_lds16(Bg + (size_t)(p * 32) * Kdim + k0, Bsw + (p * 32) * 64);
        __syncthreads();
#pragma unroll
        for (int kh = 0; kh < 2; ++kh) {
            bf16x8 af[4], bfv[4];
#pragma unroll
            for (int i = 0; i < 4; ++i)
                af[i] = frag8(As + (wm * 64 + i * 16 + l15) * 64 +
                              ((((kh << 2) + quad) ^ mkey) << 3));
#pragma unroll
            for (int j = 0; j < 4; ++j)
                bfv[j] = frag8(Bs + (wn * 64 + j * 16 + l15) * 64 +
                               ((((kh << 2) + quad) ^ mkey) << 3));
#pragma unroll
            for (int i = 0; i < 4; ++i)
#pragma unroll
                for (int j = 0; j < 4; ++j)
                    acc[i][j] = __builtin_amdgcn_mfma_f32_16x16x32_bf16(
                        af[i], bfv[j], acc[i][j], 0, 0, 0);
        }
    }
}

// ---------------- QKV GEMM ----------------
__global__ __launch_bounds__(256, 2) void gemm_qkv_k(
    const unsigned short* __restrict__ xb,
    const unsigned short* __restrict__ wt,
    const float* __restrict__ bias,
    unsigned short* __restrict__ q,
    unsigned short* __restrict__ k2,
    unsigned short* __restrict__ vt)
{
    __shared__ unsigned short Sh[128 * 132];   // mainloop uses first 32 KB
    unsigned short* As = Sh;
    unsigned short* Bs = Sh + 128 * 64;
    const int lin = blockIdx.x + 24 * blockIdx.y;        // grid 24x64 = 1536
    const int swz = (lin & 7) * 192 + (lin >> 3);        // bijective chunked
    const int n0 = (swz % 24) * 128, m0 = (swz / 24) * 128;
    f32x4 acc[4][4] = {};
    gemm128_mainloop(xb, wt, As, Bs, m0, n0, 1024, acc);

    const int tid = threadIdx.x;
    const int lane = tid & 63, wave = tid >> 6;
    const int wm = wave & 1, wn = wave >> 1;
    const int quad = lane >> 4, l15 = lane & 15;
    const bool isq = (n0 < 1024);
    const bool isv = (n0 >= 2048);
    const int cb = n0 & 1023;

    if (!isv) {
        unsigned short* outp = isq ? q : k2;
#pragma unroll
        for (int j = 0; j < 4; ++j) {
            int ct = cb + wn * 64 + j * 16 + l15;
            int h = ct >> 6, d = ct & 63;
            float bv = bias[n0 + wn * 64 + j * 16 + l15];
#pragma unroll
            for (int i = 0; i < 4; ++i)
#pragma unroll
                for (int r = 0; r < 4; ++r) {
                    int row = m0 + wm * 64 + i * 16 + quad * 4 + r;
                    int bb = row >> 11, s = row & 2047;
                    float val = acc[i][j][r] + bv;
                    if (isq) val *= 0.1803368801111244f;   // (1/8)*log2(e)
                    outp[((size_t)(bb * 16 + h) * S_LEN + s) * HD + d] = f32_bf16(val);
                }
        }
    } else {
        // ---- V: write transposed [bh][d][s] via LDS (stride 132, bank-clean)
        __syncthreads();   // all waves done with As/Bs fragment reads
#pragma unroll
        for (int j = 0; j < 4; ++j) {
            float bv = bias[n0 + wn * 64 + j * 16 + l15];
            int lc = wn * 64 + j * 16 + l15;
#pragma unroll
            for (int i = 0; i < 4; ++i)
#pragma unroll
                for (int r = 0; r < 4; ++r) {
                    int lr = wm * 64 + i * 16 + quad * 4 + r;
                    Sh[lr * 132 + lc] = f32_bf16(acc[i][j][r] + bv);
                }
        }
        __syncthreads();
        const int lc = (tid & 63) + (wave & 1) * 64;     // 0..127
        const int sh2 = wave >> 1;                       // 0..1
        const int bb = m0 >> 11;
        const int s0 = (m0 & 2047) + sh2 * 64;
        const int bh = bb * 16 + (cb >> 6) + (lc >> 6);
        unsigned short* vp = vt + ((size_t)bh * HD + (lc & 63)) * S_LEN + s0;
#pragma unroll
        for (int k8 = 0; k8 < 8; ++k8) {
            u16x8 w;
#pragma unroll
            for (int e = 0; e < 8; ++e)
                w[e] = Sh[(sh2 * 64 + k8 * 8 + e) * 132 + lc];
            *(u16x8*)(vp + k8 * 8) = w;
        }
    }
}

// ---------------- proj GEMM -> f32 out ----------------
__global__ __launch_bounds__(256, 2) void gemm_proj_k(
    const unsigned short* __restrict__ am,
    const unsigned short* __restrict__ wpt,
    const float* __restrict__ bias,
    float* __restrict__ out)
{
    __shared__ unsigned short As[128 * 64], Bs[128 * 64];
    const int lin = blockIdx.x + 8 * blockIdx.y;         // grid 8x64 = 512
    const int swz = (lin & 7) * 64 + (lin >> 3);         // bijective chunked
    const int n0 = (swz % 8) * 128, m0 = (swz / 8) * 128;
    f32x4 acc[4][4] = {};
    gemm128_mainloop(am, wpt, As, Bs, m0, n0, 1024, acc);

    const int lane = threadIdx.x & 63, wave = threadIdx.x >> 6;
    const int wm = wave & 1, wn = wave >> 1;
    const int quad = lane >> 4, l15 = lane & 15;
#pragma unroll
    for (int j = 0; j < 4; ++j) {
        int col = n0 + wn * 64 + j * 16 + l15;
        float bv = bias[col];
#pragma unroll
        for (int i = 0; i < 4; ++i)
#pragma unroll
            for (int r = 0; r < 4; ++r) {
                int row = m0 + wm * 64 + i * 16 + quad * 4 + r;
                out[(size_t)row * 1024 + col] = acc[i][j][r] + bv;
            }
    }
}

// ---------------- flash attention v12: V direct from L2, bounds kept (256,3) --
// v12 = v11 structure with __launch_bounds__(256,3): R11 proved the (256,4)
//   bound itself caused the 174 MB spill (VGPR forced 80->64); the V-unstage
//   was fine (FETCH +10 MB L2-served, passed numerically). At (256,3) the
//   allocator has slack (~170); actual use ~80-100 VGPR and LDS 34.8 KB let
//   the HW reach 4 blocks/CU on its own (occupancy = min(LDS 4, VGPR 6)).
#define PSTR 72
__global__ __launch_bounds__(256, 3) void flash_attn_k(
    const unsigned short* __restrict__ Q,
    const unsigned short* __restrict__ K,
    const unsigned short* __restrict__ Vt,
    unsigned short* __restrict__ Am)
{
    __shared__ unsigned short Ps[4 * 32 * PSTR];    // 18 KB
    __shared__ unsigned short Ks[2][64 * 64];       // 16 KB (dbuf)

    // bid -> (xcd, qt desc, bh): 128 blocks per XCD = 8 bh x 16 qt,
    // qt-major so long blocks dispatch first.
    const int bid = blockIdx.x;        // 1024 blocks
    const int xcd = bid & 7;
    const int w = bid >> 3;            // 0..127
    const int qt = 15 - (w >> 3);      // 15,15,..(x8),14,.. long-first
    const int bh = xcd * 8 + (w & 7);
    const int b = bh >> 4, h = bh & 15;
    const int tid = threadIdx.x;
    const int lane = tid & 63, wave = tid >> 6;
    const int quad = lane >> 4, l15 = lane & 15;

    const size_t bh_off = (size_t)bh * S_LEN * HD;
    const unsigned short* Kg = K + bh_off;
    const unsigned short* Vtg = Vt + (size_t)bh * HD * S_LEN;

    const int lrow = (lane >> 3) & 7;
    const int scol = ((lane & 7) ^ lrow) * 8;        // pre-swizzled source chunk
    const int srow = wave * 8 + lrow;
    const int ldst = (wave * 8) * 64 + lane * 8;     // linear LDS dest

    const int q_base = qt * 128 + wave * 32;

    // Q A-fragments, direct from global
    bf16x8 qa[2][2];
#pragma unroll
    for (int i = 0; i < 2; ++i)
#pragma unroll
        for (int kk = 0; kk < 2; ++kk)
            qa[i][kk] = frag8(Q + bh_off +
                (size_t)(q_base + i * 16 + l15) * HD + kk * 32 + quad * 8);

    f32x4 oacc[2][4] = {};
    f32x4 lacc[2] = {};
    u16x8 ones_u = {0x3F80, 0x3F80, 0x3F80, 0x3F80, 0x3F80, 0x3F80, 0x3F80, 0x3F80};
    bf16x8 vone = __builtin_bit_cast(bf16x8, ones_u);

    const int nst = 2 * qt + 2;              // uniform staging trip count
    const int nst_w = nst - ((wave < 2) ? 1 : 0);   // last tile fully masked
    unsigned short* pw = Ps + wave * (32 * PSTR);
    const int pkey = (l15 >> 2) & 3;
    const int kvkey = l15 & 7;

    // prologue: stage K tile 0 into buffer 0
#pragma unroll
    for (int pp = 0; pp < 2; ++pp)
        gload_lds16(Kg + (size_t)(srow + pp * 32) * HD + scol,
                    &Ks[0][ldst + (pp * 32) * 64]);
    __syncthreads();

    int cur = 0;
    for (int st = 0; st < nst; ++st) {
        if (st + 1 < nst) {
            const int nx = cur ^ 1;
            const size_t kroff = (size_t)((st + 1) * 64);
#pragma unroll
            for (int pp = 0; pp < 2; ++pp)
                gload_lds16(Kg + (kroff + srow + pp * 32) * HD + scol,
                            &Ks[nx][ldst + (pp * 32) * 64]);
        }
        const unsigned short* ksc = &Ks[cur][0];
        const unsigned short* vp = Vtg + st * 64;

        if (st < nst_w) {
            // S' = (Q*scale) K^T, K fragments from LDS
            f32x4 sacc[2][4] = {};
            __builtin_amdgcn_s_setprio(1);
#pragma unroll
            for (int kk = 0; kk < 2; ++kk) {
                bf16x8 kb[4];
#pragma unroll
                for (int j = 0; j < 4; ++j)
                    kb[j] = frag8(ksc + (j * 16 + l15) * 64 +
                                  ((((kk << 2) + quad) ^ kvkey) << 3));
#pragma unroll
                for (int i = 0; i < 2; ++i)
#pragma unroll
                    for (int j = 0; j < 4; ++j)
                        sacc[i][j] = __builtin_amdgcn_mfma_f32_16x16x32_bf16(
                            qa[i][kk], kb[j], sacc[i][j], 0, 0, 0);
            }
            __builtin_amdgcn_s_setprio(0);

            // causal mask (diagonal-crossing tiles only)
            if (st * 64 + 63 > q_base) {
#pragma unroll
                for (int i = 0; i < 2; ++i)
#pragma unroll
                    for (int j = 0; j < 4; ++j)
#pragma unroll
                        for (int r = 0; r < 4; ++r) {
                            int kg = st * 64 + j * 16 + l15;
                            int qg = q_base + i * 16 + quad * 4 + r;
                            if (kg > qg) sacc[i][j][r] = -__builtin_inff();
                        }
            }

            // P = exp2(s') -> bf16 (native RNE, compiler-packed) -> LDS
#pragma unroll
            for (int i = 0; i < 2; ++i)
#pragma unroll
                for (int j = 0; j < 4; ++j) {
                    int cs = ((j ^ quad) << 4) + l15;
#pragma unroll
                    for (int r = 0; r < 4; ++r)
                        pw[(i * 16 + quad * 4 + r) * PSTR + cs] =
                            f32_bf16_rn(fast_exp2(sacc[i][j][r]));
                }

            // O += P @ V ; l += P @ 1   (V fragments direct from global/L2)
#pragma unroll
            for (int kk = 0; kk < 2; ++kk) {
                bf16x8 vb[4];
#pragma unroll
                for (int d4 = 0; d4 < 4; ++d4)
                    vb[d4] = frag8(vp + (size_t)(d4 * 16 + l15) * S_LEN + kk * 32 + quad * 8);
                const int coff = ((((kk << 1) + (quad >> 1)) ^ pkey) << 4) + ((quad & 1) << 3);

                bf16x8 pa[2];
#pragma unroll
                for (int i = 0; i < 2; ++i)
                    pa[i] = frag8(pw + (i * 16 + l15) * PSTR + coff);
                __builtin_amdgcn_s_setprio(1);
#pragma unroll
                for (int d4 = 0; d4 < 4; ++d4)
#pragma unroll
                    for (int i = 0; i < 2; ++i)
                        oacc[i][d4] = __builtin_amdgcn_mfma_f32_16x16x32_bf16(
                            pa[i], vb[d4], oacc[i][d4], 0, 0, 0);
#pragma unroll
                for (int i = 0; i < 2; ++i)
                    lacc[i] = __builtin_amdgcn_mfma_f32_16x16x32_bf16(
                        pa[i], vone, lacc[i], 0, 0, 0);
                __builtin_amdgcn_s_setprio(0);
            }
        }

        // handoff: all waves done reading Ks[cur]; staging of Ks[cur^1]
        // drained by the barrier's implicit vmcnt(0)
        __syncthreads();
        cur ^= 1;
    }

    // epilogue: O / l -> merged-head bf16 [B*S][1024]
    unsigned short* Amp = Am + ((size_t)(b * S_LEN + q_base)) * D_MODEL + h * 64;
#pragma unroll
    for (int i = 0; i < 2; ++i)
#pragma unroll
        for (int r = 0; r < 4; ++r) {
            float inv = 1.f / lacc[i][r];
            int qloc = i * 16 + quad * 4 + r;
#pragma unroll
            for (int d4 = 0; d4 < 4; ++d4)
                Amp[(size_t)qloc * D_MODEL + d4 * 16 + l15] =
                    f32_bf16_rn(oacc[i][d4][r] * inv);
        }
}

// ---------------- launcher ----------------
extern "C" void kernel_launch(void* const* d_in, const int* in_sizes, int n_in,
                              void* d_out, int out_size, void* d_ws, size_t ws_size,
                              hipStream_t stream)
{
    const float* x = (const float*)d_in[0];
    const float* c_attn_w = (const float*)d_in[1];
    const float* c_attn_b = (const float*)d_in[2];
    const float* c_proj_w = (const float*)d_in[3];
    const float* c_proj_b = (const float*)d_in[4];
    float* out = (float*)d_out;

    char* ws = (char*)d_ws;
    unsigned short* xb  = (unsigned short*)(ws);              // 16 MB; reused as Am
    unsigned short* q   = (unsigned short*)(ws + 16777216);   // 16 MB
    unsigned short* k   = (unsigned short*)(ws + 33554432);   // 16 MB
    unsigned short* vt  = (unsigned short*)(ws + 67108864);   // 16 MB
    unsigned short* wqt = (unsigned short*)(ws + 83886080);   // 6 MB
    unsigned short* wpt = (unsigned short*)(ws + 90177536);   // 2 MB

    prep_k<<<12288, 256, 0, stream>>>(x, xb, c_attn_w, wqt, c_proj_w, wpt);
    gemm_qkv_k<<<dim3(24, 64), 256, 0, stream>>>(xb, wqt, c_attn_b, q, k, vt);
    flash_attn_k<<<1024, 256, 0, stream>>>(q, k, vt, xb /*Am*/);
    gemm_proj_k<<<dim3(8, 64), 256, 0, stream>>>(xb /*Am*/, wpt, c_proj_b, out);
}

// Round 13
// 252.642 us; speedup vs baseline: 1.3466x; 1.0977x over previous
//
#include <hip/hip_runtime.h>
#include <cstdint>
#include <cstddef>

#define S_LEN 2048
#define D_MODEL 1024
#define HD 64

typedef __attribute__((ext_vector_type(8))) __bf16 bf16x8;
typedef __attribute__((ext_vector_type(8))) unsigned short u16x8;
typedef __attribute__((ext_vector_type(4))) float f32x4;
typedef __attribute__((ext_vector_type(4))) unsigned short u16x4;

static __device__ __forceinline__ unsigned short f32_bf16(float f) {
    unsigned int u = __float_as_uint(f);
    u += 0x7fffu + ((u >> 16) & 1u);
    return (unsigned short)(u >> 16);
}

// native RNE cast: compiler emits v_cvt_pk_bf16_f32 for pairs (1 inst / 2 elems)
static __device__ __forceinline__ unsigned short f32_bf16_rn(float f) {
    return __builtin_bit_cast(unsigned short, (__bf16)f);
}

static __device__ __forceinline__ float fast_exp2(float x) {
#if __has_builtin(__builtin_amdgcn_exp2f)
    return __builtin_amdgcn_exp2f(x);
#else
    float r; asm("v_exp_f32 %0, %1" : "=v"(r) : "v"(x)); return r;
#endif
}

static __device__ __forceinline__ void gload_lds16(const void* g, void* l) {
    __builtin_amdgcn_global_load_lds(
        (const __attribute__((address_space(1))) unsigned int*)g,
        (__attribute__((address_space(3))) unsigned int*)l,
        16, 0, 0);
}

static __device__ __forceinline__ bf16x8 frag8(const unsigned short* p) {
    return __builtin_bit_cast(bf16x8, *(const u16x8*)p);
}

// ---------------- fused prep: x cvt + both weight transposes ----------------
__global__ void prep_k(const float* __restrict__ x, unsigned short* __restrict__ xb,
                       const float* __restrict__ caw, unsigned short* __restrict__ wqt,
                       const float* __restrict__ cpw, unsigned short* __restrict__ wpt)
{
    __shared__ float tile[32][33];
    const int blk = blockIdx.x;
    const int tid = threadIdx.x;
    if (blk < 8192) {
        int i = blk * 256 + tid;                  // exactly 2097152 f32x4
        f32x4 v = ((const f32x4*)x)[i];
        u16x4 o;
        o[0] = f32_bf16(v[0]); o[1] = f32_bf16(v[1]);
        o[2] = f32_bf16(v[2]); o[3] = f32_bf16(v[3]);
        ((u16x4*)xb)[i] = o;
        return;
    }
    const float* in; unsigned short* out; int R, C, bx, by;
    if (blk < 11264) {
        int t = blk - 8192; in = caw; out = wqt; R = 1024; C = 3072;
        bx = t % 96; by = t / 96;
    } else {
        int t = blk - 11264; in = cpw; out = wpt; R = 1024; C = 1024;
        bx = t & 31; by = t >> 5;
    }
    int tx = tid & 31, ty = tid >> 5;
    int x0 = bx * 32, y0 = by * 32;
#pragma unroll
    for (int p = 0; p < 32; p += 8)
        tile[ty + p][tx] = in[(size_t)(y0 + ty + p) * C + x0 + tx];
    __syncthreads();
#pragma unroll
    for (int p = 0; p < 32; p += 8)
        out[(size_t)(x0 + ty + p) * R + y0 + tx] = f32_bf16(tile[tx][ty + p]);
}

// ------- 128x128 NT bf16 GEMM mainloop, double-buffered 2-phase (BK=64) ------
// T3-minimum schedule (proven in flash v6): issue next tile's staging BEFORE
// computing current tile; ONE barrier per iter (implicit vmcnt drain = buffer
// handoff). As/Bs each [2][128*64]; staging latency hides under MFMA.
__device__ __forceinline__ void gemm128_mainloop_db(
    const unsigned short* __restrict__ A,
    const unsigned short* __restrict__ Bt,
    unsigned short* As, unsigned short* Bs,
    int m0, int n0, int Kdim, f32x4 acc[][4])
{
    const int tid = threadIdx.x;
    const int lane = tid & 63, wave = tid >> 6;
    const int wm = wave & 1, wn = wave >> 1;
    const int quad = lane >> 4, l15 = lane & 15;
    const int srow = wave * 8 + (lane >> 3);
    const int scol = ((lane & 7) ^ (lane >> 3)) * 8;   // swizzled chunk fetch
    const unsigned short* Ag = A + (size_t)(m0 + srow) * Kdim + scol;
    const unsigned short* Bg = Bt + (size_t)(n0 + srow) * Kdim + scol;
    const int ldst = (wave * 8) * 64 + lane * 8;       // linear LDS dest
    const int mkey = l15 & 7;

    // prologue: stage k0=0 into buffer 0
#pragma unroll
    for (int p = 0; p < 4; ++p) {
        gload_lds16(Ag + (size_t)(p * 32) * Kdim, As + ldst + (p * 32) * 64);
        gload_lds16(Bg + (size_t)(p * 32) * Kdim, Bs + ldst + (p * 32) * 64);
    }
    __syncthreads();

    int cur = 0;
    for (int k0 = 0; k0 < Kdim; k0 += 64) {
        if (k0 + 64 < Kdim) {
            const int nxo = (cur ^ 1) * 8192;
#pragma unroll
            for (int p = 0; p < 4; ++p) {
                gload_lds16(Ag + (size_t)(p * 32) * Kdim + k0 + 64,
                            As + nxo + ldst + (p * 32) * 64);
                gload_lds16(Bg + (size_t)(p * 32) * Kdim + k0 + 64,
                            Bs + nxo + ldst + (p * 32) * 64);
            }
        }
        const unsigned short* Asc = As + cur * 8192;
        const unsigned short* Bsc = Bs + cur * 8192;
#pragma unroll
        for (int kh = 0; kh < 2; ++kh) {
            bf16x8 af[4], bfv[4];
#pragma unroll
            for (int i = 0; i < 4; ++i)
                af[i] = frag8(Asc + (wm * 64 + i * 16 + l15) * 64 +
                              ((((kh << 2) + quad) ^ mkey) << 3));
#pragma unroll
            for (int j = 0; j < 4; ++j)
                bfv[j] = frag8(Bsc + (wn * 64 + j * 16 + l15) * 64 +
                               ((((kh << 2) + quad) ^ mkey) << 3));
#pragma unroll
            for (int i = 0; i < 4; ++i)
#pragma unroll
                for (int j = 0; j < 4; ++j)
                    acc[i][j] = __builtin_amdgcn_mfma_f32_16x16x32_bf16(
                        af[i], bfv[j], acc[i][j], 0, 0, 0);
        }
        // handoff: all reads of buf[cur] done; staging of buf[cur^1] drained
        __syncthreads();
        cur ^= 1;
    }
}

// ---------------- QKV GEMM ----------------
__global__ __launch_bounds__(256, 2) void gemm_qkv_k(
    const unsigned short* __restrict__ xb,
    const unsigned short* __restrict__ wt,
    const float* __restrict__ bias,
    unsigned short* __restrict__ q,
    unsigned short* __restrict__ k2,
    unsigned short* __restrict__ vt)
{
    __shared__ unsigned short Sh[4 * 8192];    // 64 KB: A dbuf + B dbuf
    unsigned short* As = Sh;
    unsigned short* Bs = Sh + 2 * 8192;
    const int lin = blockIdx.x + 24 * blockIdx.y;        // grid 24x64 = 1536
    const int swz = (lin & 7) * 192 + (lin >> 3);        // bijective chunked
    const int n0 = (swz % 24) * 128, m0 = (swz / 24) * 128;
    f32x4 acc[4][4] = {};
    gemm128_mainloop_db(xb, wt, As, Bs, m0, n0, 1024, acc);

    const int tid = threadIdx.x;
    const int lane = tid & 63, wave = tid >> 6;
    const int wm = wave & 1, wn = wave >> 1;
    const int quad = lane >> 4, l15 = lane & 15;
    const bool isq = (n0 < 1024);
    const bool isv = (n0 >= 2048);
    const int cb = n0 & 1023;

    if (!isv) {
        unsigned short* outp = isq ? q : k2;
#pragma unroll
        for (int j = 0; j < 4; ++j) {
            int ct = cb + wn * 64 + j * 16 + l15;
            int h = ct >> 6, d = ct & 63;
            float bv = bias[n0 + wn * 64 + j * 16 + l15];
#pragma unroll
            for (int i = 0; i < 4; ++i)
#pragma unroll
                for (int r = 0; r < 4; ++r) {
                    int row = m0 + wm * 64 + i * 16 + quad * 4 + r;
                    int bb = row >> 11, s = row & 2047;
                    float val = acc[i][j][r] + bv;
                    if (isq) val *= 0.1803368801111244f;   // (1/8)*log2(e)
                    outp[((size_t)(bb * 16 + h) * S_LEN + s) * HD + d] = f32_bf16(val);
                }
        }
    } else {
        // ---- V: write transposed [bh][d][s] via LDS (stride 132, bank-clean)
        __syncthreads();   // all waves past final mainloop barrier
#pragma unroll
        for (int j = 0; j < 4; ++j) {
            float bv = bias[n0 + wn * 64 + j * 16 + l15];
            int lc = wn * 64 + j * 16 + l15;
#pragma unroll
            for (int i = 0; i < 4; ++i)
#pragma unroll
                for (int r = 0; r < 4; ++r) {
                    int lr = wm * 64 + i * 16 + quad * 4 + r;
                    Sh[lr * 132 + lc] = f32_bf16(acc[i][j][r] + bv);
                }
        }
        __syncthreads();
        const int lc = (tid & 63) + (wave & 1) * 64;     // 0..127
        const int sh2 = wave >> 1;                       // 0..1
        const int bb = m0 >> 11;
        const int s0 = (m0 & 2047) + sh2 * 64;
        const int bh = bb * 16 + (cb >> 6) + (lc >> 6);
        unsigned short* vp = vt + ((size_t)bh * HD + (lc & 63)) * S_LEN + s0;
#pragma unroll
        for (int k8 = 0; k8 < 8; ++k8) {
            u16x8 w;
#pragma unroll
            for (int e = 0; e < 8; ++e)
                w[e] = Sh[(sh2 * 64 + k8 * 8 + e) * 132 + lc];
            *(u16x8*)(vp + k8 * 8) = w;
        }
    }
}

// ---------------- proj GEMM -> f32 out ----------------
__global__ __launch_bounds__(256, 2) void gemm_proj_k(
    const unsigned short* __restrict__ am,
    const unsigned short* __restrict__ wpt,
    const float* __restrict__ bias,
    float* __restrict__ out)
{
    __shared__ unsigned short As[2 * 8192], Bs[2 * 8192];   // 64 KB dbuf
    const int lin = blockIdx.x + 8 * blockIdx.y;         // grid 8x64 = 512
    const int swz = (lin & 7) * 64 + (lin >> 3);         // bijective chunked
    const int n0 = (swz % 8) * 128, m0 = (swz / 8) * 128;
    f32x4 acc[4][4] = {};
    gemm128_mainloop_db(am, wpt, As, Bs, m0, n0, 1024, acc);

    const int lane = threadIdx.x & 63, wave = threadIdx.x >> 6;
    const int wm = wave & 1, wn = wave >> 1;
    const int quad = lane >> 4, l15 = lane & 15;
#pragma unroll
    for (int j = 0; j < 4; ++j) {
        int col = n0 + wn * 64 + j * 16 + l15;
        float bv = bias[col];
#pragma unroll
        for (int i = 0; i < 4; ++i)
#pragma unroll
            for (int r = 0; r < 4; ++r) {
                int row = m0 + wm * 64 + i * 16 + quad * 4 + r;
                out[(size_t)row * 1024 + col] = acc[i][j][r] + bv;
            }
    }
}

// ---------------- flash attention v10 (restored): 1024 blocks, K+V staged ----
// R12 proved V-staging is load-bearing (V-direct: MfmaUtil 26->17, 60->92us).
// v10 exact: one q-tile per block, 64bh x 16qt grid, qt-desc dispatch,
// bh-major XCD map, K/V dbuf via global_load_lds, setprio, native RNE cvt.
#define PSTR 72
__global__ __launch_bounds__(256, 3) void flash_attn_k(
    const unsigned short* __restrict__ Q,
    const unsigned short* __restrict__ K,
    const unsigned short* __restrict__ Vt,
    unsigned short* __restrict__ Am)
{
    __shared__ unsigned short Ps[4 * 32 * PSTR];    // 18 KB
    __shared__ unsigned short Ks[2][64 * 64];       // 16 KB (dbuf)
    __shared__ unsigned short Vs[2][64 * 64];       // 16 KB (dbuf)

    const int bid = blockIdx.x;        // 1024 blocks
    const int xcd = bid & 7;
    const int w = bid >> 3;            // 0..127
    const int qt = 15 - (w >> 3);      // 15,15,..(x8),14,.. long-first
    const int bh = xcd * 8 + (w & 7);
    const int b = bh >> 4, h = bh & 15;
    const int tid = threadIdx.x;
    const int lane = tid & 63, wave = tid >> 6;
    const int quad = lane >> 4, l15 = lane & 15;

    const size_t bh_off = (size_t)bh * S_LEN * HD;
    const unsigned short* Kg = K + bh_off;
    const unsigned short* Vtg = Vt + (size_t)bh * HD * S_LEN;

    const int lrow = (lane >> 3) & 7;
    const int scol = ((lane & 7) ^ lrow) * 8;        // pre-swizzled source chunk
    const int srow = wave * 8 + lrow;
    const int ldst = (wave * 8) * 64 + lane * 8;     // linear LDS dest

    const int q_base = qt * 128 + wave * 32;

    // Q A-fragments, direct from global
    bf16x8 qa[2][2];
#pragma unroll
    for (int i = 0; i < 2; ++i)
#pragma unroll
        for (int kk = 0; kk < 2; ++kk)
            qa[i][kk] = frag8(Q + bh_off +
                (size_t)(q_base + i * 16 + l15) * HD + kk * 32 + quad * 8);

    f32x4 oacc[2][4] = {};
    f32x4 lacc[2] = {};
    u16x8 ones_u = {0x3F80, 0x3F80, 0x3F80, 0x3F80, 0x3F80, 0x3F80, 0x3F80, 0x3F80};
    bf16x8 vone = __builtin_bit_cast(bf16x8, ones_u);

    const int nst = 2 * qt + 2;              // uniform staging trip count
    const int nst_w = nst - ((wave < 2) ? 1 : 0);   // last tile fully masked
    unsigned short* pw = Ps + wave * (32 * PSTR);
    const int pkey = (l15 >> 2) & 3;
    const int kvkey = l15 & 7;

    // prologue: stage tile 0 into buffer 0
#pragma unroll
    for (int pp = 0; pp < 2; ++pp) {
        gload_lds16(Kg + (size_t)(srow + pp * 32) * HD + scol,
                    &Ks[0][ldst + (pp * 32) * 64]);
        gload_lds16(Vtg + (size_t)(srow + pp * 32) * S_LEN + scol,
                    &Vs[0][ldst + (pp * 32) * 64]);
    }
    __syncthreads();

    int cur = 0;
    for (int st = 0; st < nst; ++st) {
        if (st + 1 < nst) {
            const int nx = cur ^ 1;
            const size_t kroff = (size_t)((st + 1) * 64);
#pragma unroll
            for (int pp = 0; pp < 2; ++pp) {
                gload_lds16(Kg + (kroff + srow + pp * 32) * HD + scol,
                            &Ks[nx][ldst + (pp * 32) * 64]);
                gload_lds16(Vtg + (size_t)(srow + pp * 32) * S_LEN + kroff + scol,
                            &Vs[nx][ldst + (pp * 32) * 64]);
            }
        }
        const unsigned short* ksc = &Ks[cur][0];
        const unsigned short* vsc = &Vs[cur][0];

        if (st < nst_w) {
            // S' = (Q*scale) K^T, K fragments from LDS
            f32x4 sacc[2][4] = {};
            __builtin_amdgcn_s_setprio(1);
#pragma unroll
            for (int kk = 0; kk < 2; ++kk) {
                bf16x8 kb[4];
#pragma unroll
                for (int j = 0; j < 4; ++j)
                    kb[j] = frag8(ksc + (j * 16 + l15) * 64 +
                                  ((((kk << 2) + quad) ^ kvkey) << 3));
#pragma unroll
                for (int i = 0; i < 2; ++i)
#pragma unroll
                    for (int j = 0; j < 4; ++j)
                        sacc[i][j] = __builtin_amdgcn_mfma_f32_16x16x32_bf16(
                            qa[i][kk], kb[j], sacc[i][j], 0, 0, 0);
            }
            __builtin_amdgcn_s_setprio(0);

            // causal mask (diagonal-crossing tiles only)
            if (st * 64 + 63 > q_base) {
#pragma unroll
                for (int i = 0; i < 2; ++i)
#pragma unroll
                    for (int j = 0; j < 4; ++j)
#pragma unroll
                        for (int r = 0; r < 4; ++r) {
                            int kg = st * 64 + j * 16 + l15;
                            int qg = q_base + i * 16 + quad * 4 + r;
                            if (kg > qg) sacc[i][j][r] = -__builtin_inff();
                        }
            }

            // P = exp2(s') -> bf16 (native RNE, compiler-packed) -> LDS
#pragma unroll
            for (int i = 0; i < 2; ++i)
#pragma unroll
                for (int j = 0; j < 4; ++j) {
                    int cs = ((j ^ quad) << 4) + l15;
#pragma unroll
                    for (int r = 0; r < 4; ++r)
                        pw[(i * 16 + quad * 4 + r) * PSTR + cs] =
                            f32_bf16_rn(fast_exp2(sacc[i][j][r]));
                }

            // O += P @ V ; l += P @ 1   (V fragments from LDS, per-kk)
#pragma unroll
            for (int kk = 0; kk < 2; ++kk) {
                bf16x8 vb[4];
#pragma unroll
                for (int d4 = 0; d4 < 4; ++d4)
                    vb[d4] = frag8(vsc + (d4 * 16 + l15) * 64 +
                                   ((((kk << 2) + quad) ^ kvkey) << 3));
                const int coff = ((((kk << 1) + (quad >> 1)) ^ pkey) << 4) + ((quad & 1) << 3);

                bf16x8 pa[2];
#pragma unroll
                for (int i = 0; i < 2; ++i)
                    pa[i] = frag8(pw + (i * 16 + l15) * PSTR + coff);
                __builtin_amdgcn_s_setprio(1);
#pragma unroll
                for (int d4 = 0; d4 < 4; ++d4)
#pragma unroll
                    for (int i = 0; i < 2; ++i)
                        oacc[i][d4] = __builtin_amdgcn_mfma_f32_16x16x32_bf16(
                            pa[i], vb[d4], oacc[i][d4], 0, 0, 0);
#pragma unroll
                for (int i = 0; i < 2; ++i)
                    lacc[i] = __builtin_amdgcn_mfma_f32_16x16x32_bf16(
                        pa[i], vone, lacc[i], 0, 0, 0);
                __builtin_amdgcn_s_setprio(0);
            }
        }

        // handoff: all waves done reading buf[cur]; staging of buf[cur^1]
        // drained by the barrier's implicit vmcnt(0)
        __syncthreads();
        cur ^= 1;
    }

    // epilogue: O / l -> merged-head bf16 [B*S][1024]
    unsigned short* Amp = Am + ((size_t)(b * S_LEN + q_base)) * D_MODEL + h * 64;
#pragma unroll
    for (int i = 0; i < 2; ++i)
#pragma unroll
        for (int r = 0; r < 4; ++r) {
            float inv = 1.f / lacc[i][r];
            int qloc = i * 16 + quad * 4 + r;
#pragma unroll
            for (int d4 = 0; d4 < 4; ++d4)
                Amp[(size_t)qloc * D_MODEL + d4 * 16 + l15] =
                    f32_bf16_rn(oacc[i][d4][r] * inv);
        }
}

// ---------------- launcher ----------------
extern "C" void kernel_launch(void* const* d_in, const int* in_sizes, int n_in,
                              void* d_out, int out_size, void* d_ws, size_t ws_size,
                              hipStream_t stream)
{
    const float* x = (const float*)d_in[0];
    const float* c_attn_w = (const float*)d_in[1];
    const float* c_attn_b = (const float*)d_in[2];
    const float* c_proj_w = (const float*)d_in[3];
    const float* c_proj_b = (const float*)d_in[4];
    float* out = (float*)d_out;

    char* ws = (char*)d_ws;
    unsigned short* xb  = (unsigned short*)(ws);              // 16 MB; reused as Am
    unsigned short* q   = (unsigned short*)(ws + 16777216);   // 16 MB
    unsigned short* k   = (unsigned short*)(ws + 33554432);   // 16 MB
    unsigned short* vt  = (unsigned short*)(ws + 67108864);   // 16 MB
    unsigned short* wqt = (unsigned short*)(ws + 83886080);   // 6 MB
    unsigned short* wpt = (unsigned short*)(ws + 90177536);   // 2 MB

    prep_k<<<12288, 256, 0, stream>>>(x, xb, c_attn_w, wqt, c_proj_w, wpt);
    gemm_qkv_k<<<dim3(24, 64), 256, 0, stream>>>(xb, wqt, c_attn_b, q, k, vt);
    flash_attn_k<<<1024, 256, 0, stream>>>(q, k, vt, xb /*Am*/);
    gemm_proj_k<<<dim3(8, 64), 256, 0, stream>>>(xb /*Am*/, wpt, c_proj_b, out);
}

// Round 14
// 250.721 us; speedup vs baseline: 1.3570x; 1.0077x over previous
//
#include <hip/hip_runtime.h>
#include <cstdint>
#include <cstddef>

#define S_LEN 2048
#define D_MODEL 1024
#define HD 64

typedef __attribute__((ext_vector_type(8))) __bf16 bf16x8;
typedef __attribute__((ext_vector_type(8))) unsigned short u16x8;
typedef __attribute__((ext_vector_type(4))) float f32x4;
typedef __attribute__((ext_vector_type(4))) unsigned short u16x4;

static __device__ __forceinline__ unsigned short f32_bf16(float f) {
    unsigned int u = __float_as_uint(f);
    u += 0x7fffu + ((u >> 16) & 1u);
    return (unsigned short)(u >> 16);
}

// native RNE cast: compiler emits v_cvt_pk_bf16_f32 for pairs (1 inst / 2 elems)
static __device__ __forceinline__ unsigned short f32_bf16_rn(float f) {
    return __builtin_bit_cast(unsigned short, (__bf16)f);
}

static __device__ __forceinline__ float fast_exp2(float x) {
#if __has_builtin(__builtin_amdgcn_exp2f)
    return __builtin_amdgcn_exp2f(x);
#else
    float r; asm("v_exp_f32 %0, %1" : "=v"(r) : "v"(x)); return r;
#endif
}

static __device__ __forceinline__ void gload_lds16(const void* g, void* l) {
    __builtin_amdgcn_global_load_lds(
        (const __attribute__((address_space(1))) unsigned int*)g,
        (__attribute__((address_space(3))) unsigned int*)l,
        16, 0, 0);
}

static __device__ __forceinline__ bf16x8 frag8(const unsigned short* p) {
    return __builtin_bit_cast(bf16x8, *(const u16x8*)p);
}

// ---------------- fused prep: x cvt + both weight transposes ----------------
__global__ void prep_k(const float* __restrict__ x, unsigned short* __restrict__ xb,
                       const float* __restrict__ caw, unsigned short* __restrict__ wqt,
                       const float* __restrict__ cpw, unsigned short* __restrict__ wpt)
{
    __shared__ float tile[32][33];
    const int blk = blockIdx.x;
    const int tid = threadIdx.x;
    if (blk < 8192) {
        int i = blk * 256 + tid;                  // exactly 2097152 f32x4
        f32x4 v = ((const f32x4*)x)[i];
        u16x4 o;
        o[0] = f32_bf16(v[0]); o[1] = f32_bf16(v[1]);
        o[2] = f32_bf16(v[2]); o[3] = f32_bf16(v[3]);
        ((u16x4*)xb)[i] = o;
        return;
    }
    const float* in; unsigned short* out; int R, C, bx, by;
    if (blk < 11264) {
        int t = blk - 8192; in = caw; out = wqt; R = 1024; C = 3072;
        bx = t % 96; by = t / 96;
    } else {
        int t = blk - 11264; in = cpw; out = wpt; R = 1024; C = 1024;
        bx = t & 31; by = t >> 5;
    }
    int tx = tid & 31, ty = tid >> 5;
    int x0 = bx * 32, y0 = by * 32;
#pragma unroll
    for (int p = 0; p < 32; p += 8)
        tile[ty + p][tx] = in[(size_t)(y0 + ty + p) * C + x0 + tx];
    __syncthreads();
#pragma unroll
    for (int p = 0; p < 32; p += 8)
        out[(size_t)(x0 + ty + p) * R + y0 + tx] = f32_bf16(tile[tx][ty + p]);
}

// ---------------- shared 128x128 NT bf16 GEMM mainloop (BK=64) ----------------
// Single-buffered: 32 KB LDS -> 4 resident blocks/CU; R13 proved dbuf (64 KB,
// 2 blocks/CU) regresses -8% — cross-block wave overlap (m114) beats
// source-level pipelining at this tile size.
__device__ __forceinline__ void gemm128_mainloop(
    const unsigned short* __restrict__ A,
    const unsigned short* __restrict__ Bt,
    unsigned short* As, unsigned short* Bs,
    int m0, int n0, int Kdim, f32x4 acc[][4])
{
    const int tid = threadIdx.x;
    const int lane = tid & 63, wave = tid >> 6;
    const int wm = wave & 1, wn = wave >> 1;
    const int quad = lane >> 4, l15 = lane & 15;
    const int srow = wave * 8 + (lane >> 3);
    const int scol = ((lane & 7) ^ (lane >> 3)) * 8;   // swizzled chunk fetch
    const unsigned short* Ag = A + (size_t)(m0 + srow) * Kdim + scol;
    const unsigned short* Bg = Bt + (size_t)(n0 + srow) * Kdim + scol;
    unsigned short* Asw = As + (wave * 8) * 64 + lane * 8;
    unsigned short* Bsw = Bs + (wave * 8) * 64 + lane * 8;
    const int mkey = l15 & 7;

    for (int k0 = 0; k0 < Kdim; k0 += 64) {
        __syncthreads();
#pragma unroll
        for (int p = 0; p < 4; ++p)
            gload_lds16(Ag + (size_t)(p * 32) * Kdim + k0, Asw + (p * 32) * 64);
#pragma unroll
        for (int p = 0; p < 4; ++p)
            gload_lds16(Bg + (size_t)(p * 32) * Kdim + k0, Bsw + (p * 32) * 64);
        __syncthreads();
#pragma unroll
        for (int kh = 0; kh < 2; ++kh) {
            bf16x8 af[4], bfv[4];
#pragma unroll
            for (int i = 0; i < 4; ++i)
                af[i] = frag8(As + (wm * 64 + i * 16 + l15) * 64 +
                              ((((kh << 2) + quad) ^ mkey) << 3));
#pragma unroll
            for (int j = 0; j < 4; ++j)
                bfv[j] = frag8(Bs + (wn * 64 + j * 16 + l15) * 64 +
                               ((((kh << 2) + quad) ^ mkey) << 3));
#pragma unroll
            for (int i = 0; i < 4; ++i)
#pragma unroll
                for (int j = 0; j < 4; ++j)
                    acc[i][j] = __builtin_amdgcn_mfma_f32_16x16x32_bf16(
                        af[i], bfv[j], acc[i][j], 0, 0, 0);
        }
    }
}

// ---------------- QKV GEMM ----------------
__global__ __launch_bounds__(256, 2) void gemm_qkv_k(
    const unsigned short* __restrict__ xb,
    const unsigned short* __restrict__ wt,
    const float* __restrict__ bias,
    unsigned short* __restrict__ q,
    unsigned short* __restrict__ k2,
    unsigned short* __restrict__ vt)
{
    __shared__ unsigned short Sh[128 * 132];   // mainloop uses first 32 KB
    unsigned short* As = Sh;
    unsigned short* Bs = Sh + 128 * 64;
    const int lin = blockIdx.x + 24 * blockIdx.y;        // grid 24x64 = 1536
    const int swz = (lin & 7) * 192 + (lin >> 3);        // bijective chunked
    const int n0 = (swz % 24) * 128, m0 = (swz / 24) * 128;
    f32x4 acc[4][4] = {};
    gemm128_mainloop(xb, wt, As, Bs, m0, n0, 1024, acc);

    const int tid = threadIdx.x;
    const int lane = tid & 63, wave = tid >> 6;
    const int wm = wave & 1, wn = wave >> 1;
    const int quad = lane >> 4, l15 = lane & 15;
    const bool isq = (n0 < 1024);
    const bool isv = (n0 >= 2048);
    const int cb = n0 & 1023;

    if (!isv) {
        unsigned short* outp = isq ? q : k2;
#pragma unroll
        for (int j = 0; j < 4; ++j) {
            int ct = cb + wn * 64 + j * 16 + l15;
            int h = ct >> 6, d = ct & 63;
            float bv = bias[n0 + wn * 64 + j * 16 + l15];
#pragma unroll
            for (int i = 0; i < 4; ++i)
#pragma unroll
                for (int r = 0; r < 4; ++r) {
                    int row = m0 + wm * 64 + i * 16 + quad * 4 + r;
                    int bb = row >> 11, s = row & 2047;
                    float val = acc[i][j][r] + bv;
                    if (isq) val *= 0.1803368801111244f;   // (1/8)*log2(e)
                    outp[((size_t)(bb * 16 + h) * S_LEN + s) * HD + d] = f32_bf16(val);
                }
        }
    } else {
        // ---- V: write transposed [bh][d][s] via LDS (stride 132, bank-clean)
        __syncthreads();   // all waves done with As/Bs fragment reads
#pragma unroll
        for (int j = 0; j < 4; ++j) {
            float bv = bias[n0 + wn * 64 + j * 16 + l15];
            int lc = wn * 64 + j * 16 + l15;
#pragma unroll
            for (int i = 0; i < 4; ++i)
#pragma unroll
                for (int r = 0; r < 4; ++r) {
                    int lr = wm * 64 + i * 16 + quad * 4 + r;
                    Sh[lr * 132 + lc] = f32_bf16(acc[i][j][r] + bv);
                }
        }
        __syncthreads();
        const int lc = (tid & 63) + (wave & 1) * 64;     // 0..127
        const int sh2 = wave >> 1;                       // 0..1
        const int bb = m0 >> 11;
        const int s0 = (m0 & 2047) + sh2 * 64;
        const int bh = bb * 16 + (cb >> 6) + (lc >> 6);
        unsigned short* vp = vt + ((size_t)bh * HD + (lc & 63)) * S_LEN + s0;
#pragma unroll
        for (int k8 = 0; k8 < 8; ++k8) {
            u16x8 w;
#pragma unroll
            for (int e = 0; e < 8; ++e)
                w[e] = Sh[(sh2 * 64 + k8 * 8 + e) * 132 + lc];
            *(u16x8*)(vp + k8 * 8) = w;
        }
    }
}

// ---------------- proj GEMM -> f32 out ----------------
__global__ __launch_bounds__(256, 2) void gemm_proj_k(
    const unsigned short* __restrict__ am,
    const unsigned short* __restrict__ wpt,
    const float* __restrict__ bias,
    float* __restrict__ out)
{
    __shared__ unsigned short As[128 * 64], Bs[128 * 64];
    const int lin = blockIdx.x + 8 * blockIdx.y;         // grid 8x64 = 512
    const int swz = (lin & 7) * 64 + (lin >> 3);         // bijective chunked
    const int n0 = (swz % 8) * 128, m0 = (swz / 8) * 128;
    f32x4 acc[4][4] = {};
    gemm128_mainloop(am, wpt, As, Bs, m0, n0, 1024, acc);

    const int lane = threadIdx.x & 63, wave = threadIdx.x >> 6;
    const int wm = wave & 1, wn = wave >> 1;
    const int quad = lane >> 4, l15 = lane & 15;
#pragma unroll
    for (int j = 0; j < 4; ++j) {
        int col = n0 + wn * 64 + j * 16 + l15;
        float bv = bias[col];
#pragma unroll
        for (int i = 0; i < 4; ++i)
#pragma unroll
            for (int r = 0; r < 4; ++r) {
                int row = m0 + wm * 64 + i * 16 + quad * 4 + r;
                out[(size_t)row * 1024 + col] = acc[i][j][r] + bv;
            }
    }
}

// ---------------- flash attention v10: 1024 blocks, K+V staged, 3 blocks/CU --
// Best verified flash (R10: 60.4us, MfmaUtil 26%). One q-tile per block,
// 64bh x 16qt grid, qt-desc dispatch, bh-major XCD map, K/V dbuf via
// global_load_lds, setprio on MFMA, native RNE cvt, wave-0/1 masked-tile skip.
// R12 proved V-staging is load-bearing; R11 proved launch_bounds must stay
// (256,3) — forcing 4 waves/EU spills catastrophically.
#define PSTR 72
__global__ __launch_bounds__(256, 3) void flash_attn_k(
    const unsigned short* __restrict__ Q,
    const unsigned short* __restrict__ K,
    const unsigned short* __restrict__ Vt,
    unsigned short* __restrict__ Am)
{
    __shared__ unsigned short Ps[4 * 32 * PSTR];    // 18 KB
    __shared__ unsigned short Ks[2][64 * 64];       // 16 KB (dbuf)
    __shared__ unsigned short Vs[2][64 * 64];       // 16 KB (dbuf)

    const int bid = blockIdx.x;        // 1024 blocks
    const int xcd = bid & 7;
    const int w = bid >> 3;            // 0..127
    const int qt = 15 - (w >> 3);      // 15,15,..(x8),14,.. long-first
    const int bh = xcd * 8 + (w & 7);
    const int b = bh >> 4, h = bh & 15;
    const int tid = threadIdx.x;
    const int lane = tid & 63, wave = tid >> 6;
    const int quad = lane >> 4, l15 = lane & 15;

    const size_t bh_off = (size_t)bh * S_LEN * HD;
    const unsigned short* Kg = K + bh_off;
    const unsigned short* Vtg = Vt + (size_t)bh * HD * S_LEN;

    const int lrow = (lane >> 3) & 7;
    const int scol = ((lane & 7) ^ lrow) * 8;        // pre-swizzled source chunk
    const int srow = wave * 8 + lrow;
    const int ldst = (wave * 8) * 64 + lane * 8;     // linear LDS dest

    const int q_base = qt * 128 + wave * 32;

    // Q A-fragments, direct from global
    bf16x8 qa[2][2];
#pragma unroll
    for (int i = 0; i < 2; ++i)
#pragma unroll
        for (int kk = 0; kk < 2; ++kk)
            qa[i][kk] = frag8(Q + bh_off +
                (size_t)(q_base + i * 16 + l15) * HD + kk * 32 + quad * 8);

    f32x4 oacc[2][4] = {};
    f32x4 lacc[2] = {};
    u16x8 ones_u = {0x3F80, 0x3F80, 0x3F80, 0x3F80, 0x3F80, 0x3F80, 0x3F80, 0x3F80};
    bf16x8 vone = __builtin_bit_cast(bf16x8, ones_u);

    const int nst = 2 * qt + 2;              // uniform staging trip count
    const int nst_w = nst - ((wave < 2) ? 1 : 0);   // last tile fully masked
    unsigned short* pw = Ps + wave * (32 * PSTR);
    const int pkey = (l15 >> 2) & 3;
    const int kvkey = l15 & 7;

    // prologue: stage tile 0 into buffer 0
#pragma unroll
    for (int pp = 0; pp < 2; ++pp) {
        gload_lds16(Kg + (size_t)(srow + pp * 32) * HD + scol,
                    &Ks[0][ldst + (pp * 32) * 64]);
        gload_lds16(Vtg + (size_t)(srow + pp * 32) * S_LEN + scol,
                    &Vs[0][ldst + (pp * 32) * 64]);
    }
    __syncthreads();

    int cur = 0;
    for (int st = 0; st < nst; ++st) {
        if (st + 1 < nst) {
            const int nx = cur ^ 1;
            const size_t kroff = (size_t)((st + 1) * 64);
#pragma unroll
            for (int pp = 0; pp < 2; ++pp) {
                gload_lds16(Kg + (kroff + srow + pp * 32) * HD + scol,
                            &Ks[nx][ldst + (pp * 32) * 64]);
                gload_lds16(Vtg + (size_t)(srow + pp * 32) * S_LEN + kroff + scol,
                            &Vs[nx][ldst + (pp * 32) * 64]);
            }
        }
        const unsigned short* ksc = &Ks[cur][0];
        const unsigned short* vsc = &Vs[cur][0];

        if (st < nst_w) {
            // S' = (Q*scale) K^T, K fragments from LDS
            f32x4 sacc[2][4] = {};
            __builtin_amdgcn_s_setprio(1);
#pragma unroll
            for (int kk = 0; kk < 2; ++kk) {
                bf16x8 kb[4];
#pragma unroll
                for (int j = 0; j < 4; ++j)
                    kb[j] = frag8(ksc + (j * 16 + l15) * 64 +
                                  ((((kk << 2) + quad) ^ kvkey) << 3));
#pragma unroll
                for (int i = 0; i < 2; ++i)
#pragma unroll
                    for (int j = 0; j < 4; ++j)
                        sacc[i][j] = __builtin_amdgcn_mfma_f32_16x16x32_bf16(
                            qa[i][kk], kb[j], sacc[i][j], 0, 0, 0);
            }
            __builtin_amdgcn_s_setprio(0);

            // causal mask (diagonal-crossing tiles only)
            if (st * 64 + 63 > q_base) {
#pragma unroll
                for (int i = 0; i < 2; ++i)
#pragma unroll
                    for (int j = 0; j < 4; ++j)
#pragma unroll
                        for (int r = 0; r < 4; ++r) {
                            int kg = st * 64 + j * 16 + l15;
                            int qg = q_base + i * 16 + quad * 4 + r;
                            if (kg > qg) sacc[i][j][r] = -__builtin_inff();
                        }
            }

            // P = exp2(s') -> bf16 (native RNE, compiler-packed) -> LDS
#pragma unroll
            for (int i = 0; i < 2; ++i)
#pragma unroll
                for (int j = 0; j < 4; ++j) {
                    int cs = ((j ^ quad) << 4) + l15;
#pragma unroll
                    for (int r = 0; r < 4; ++r)
                        pw[(i * 16 + quad * 4 + r) * PSTR + cs] =
                            f32_bf16_rn(fast_exp2(sacc[i][j][r]));
                }

            // O += P @ V ; l += P @ 1   (V fragments from LDS, per-kk)
#pragma unroll
            for (int kk = 0; kk < 2; ++kk) {
                bf16x8 vb[4];
#pragma unroll
                for (int d4 = 0; d4 < 4; ++d4)
                    vb[d4] = frag8(vsc + (d4 * 16 + l15) * 64 +
                                   ((((kk << 2) + quad) ^ kvkey) << 3));
                const int coff = ((((kk << 1) + (quad >> 1)) ^ pkey) << 4) + ((quad & 1) << 3);

                bf16x8 pa[2];
#pragma unroll
                for (int i = 0; i < 2; ++i)
                    pa[i] = frag8(pw + (i * 16 + l15) * PSTR + coff);
                __builtin_amdgcn_s_setprio(1);
#pragma unroll
                for (int d4 = 0; d4 < 4; ++d4)
#pragma unroll
                    for (int i = 0; i < 2; ++i)
                        oacc[i][d4] = __builtin_amdgcn_mfma_f32_16x16x32_bf16(
                            pa[i], vb[d4], oacc[i][d4], 0, 0, 0);
#pragma unroll
                for (int i = 0; i < 2; ++i)
                    lacc[i] = __builtin_amdgcn_mfma_f32_16x16x32_bf16(
                        pa[i], vone, lacc[i], 0, 0, 0);
                __builtin_amdgcn_s_setprio(0);
            }
        }

        // handoff: all waves done reading buf[cur]; staging of buf[cur^1]
        // drained by the barrier's implicit vmcnt(0)
        __syncthreads();
        cur ^= 1;
    }

    // epilogue: O / l -> merged-head bf16 [B*S][1024]
    unsigned short* Amp = Am + ((size_t)(b * S_LEN + q_base)) * D_MODEL + h * 64;
#pragma unroll
    for (int i = 0; i < 2; ++i)
#pragma unroll
        for (int r = 0; r < 4; ++r) {
            float inv = 1.f / lacc[i][r];
            int qloc = i * 16 + quad * 4 + r;
#pragma unroll
            for (int d4 = 0; d4 < 4; ++d4)
                Amp[(size_t)qloc * D_MODEL + d4 * 16 + l15] =
                    f32_bf16_rn(oacc[i][d4][r] * inv);
        }
}

// ---------------- launcher ----------------
extern "C" void kernel_launch(void* const* d_in, const int* in_sizes, int n_in,
                              void* d_out, int out_size, void* d_ws, size_t ws_size,
                              hipStream_t stream)
{
    const float* x = (const float*)d_in[0];
    const float* c_attn_w = (const float*)d_in[1];
    const float* c_attn_b = (const float*)d_in[2];
    const float* c_proj_w = (const float*)d_in[3];
    const float* c_proj_b = (const float*)d_in[4];
    float* out = (float*)d_out;

    char* ws = (char*)d_ws;
    unsigned short* xb  = (unsigned short*)(ws);              // 16 MB; reused as Am
    unsigned short* q   = (unsigned short*)(ws + 16777216);   // 16 MB
    unsigned short* k   = (unsigned short*)(ws + 33554432);   // 16 MB
    unsigned short* vt  = (unsigned short*)(ws + 67108864);   // 16 MB
    unsigned short* wqt = (unsigned short*)(ws + 83886080);   // 6 MB
    unsigned short* wpt = (unsigned short*)(ws + 90177536);   // 2 MB

    prep_k<<<12288, 256, 0, stream>>>(x, xb, c_attn_w, wqt, c_proj_w, wpt);
    gemm_qkv_k<<<dim3(24, 64), 256, 0, stream>>>(xb, wqt, c_attn_b, q, k, vt);
    flash_attn_k<<<1024, 256, 0, stream>>>(q, k, vt, xb /*Am*/);
    gemm_proj_k<<<dim3(8, 64), 256, 0, stream>>>(xb /*Am*/, wpt, c_proj_b, out);
}

// Round 15
// 244.780 us; speedup vs baseline: 1.3899x; 1.0243x over previous
//
#include <hip/hip_runtime.h>
#include <cstdint>
#include <cstddef>

#define S_LEN 2048
#define D_MODEL 1024
#define HD 64

typedef __attribute__((ext_vector_type(8))) __bf16 bf16x8;
typedef __attribute__((ext_vector_type(8))) unsigned short u16x8;
typedef __attribute__((ext_vector_type(4))) float f32x4;
typedef __attribute__((ext_vector_type(4))) unsigned short u16x4;

static __device__ __forceinline__ unsigned short f32_bf16(float f) {
    unsigned int u = __float_as_uint(f);
    u += 0x7fffu + ((u >> 16) & 1u);
    return (unsigned short)(u >> 16);
}

// native RNE cast: compiler emits v_cvt_pk_bf16_f32 for pairs (1 inst / 2 elems)
static __device__ __forceinline__ unsigned short f32_bf16_rn(float f) {
    return __builtin_bit_cast(unsigned short, (__bf16)f);
}

static __device__ __forceinline__ float fast_exp2(float x) {
#if __has_builtin(__builtin_amdgcn_exp2f)
    return __builtin_amdgcn_exp2f(x);
#else
    float r; asm("v_exp_f32 %0, %1" : "=v"(r) : "v"(x)); return r;
#endif
}

static __device__ __forceinline__ void gload_lds16(const void* g, void* l) {
    __builtin_amdgcn_global_load_lds(
        (const __attribute__((address_space(1))) unsigned int*)g,
        (__attribute__((address_space(3))) unsigned int*)l,
        16, 0, 0);
}

static __device__ __forceinline__ bf16x8 frag8(const unsigned short* p) {
    return __builtin_bit_cast(bf16x8, *(const u16x8*)p);
}

// ---------------- fused prep: x cvt + both weight transposes ----------------
__global__ void prep_k(const float* __restrict__ x, unsigned short* __restrict__ xb,
                       const float* __restrict__ caw, unsigned short* __restrict__ wqt,
                       const float* __restrict__ cpw, unsigned short* __restrict__ wpt)
{
    __shared__ float tile[32][33];
    const int blk = blockIdx.x;
    const int tid = threadIdx.x;
    if (blk < 8192) {
        int i = blk * 256 + tid;                  // exactly 2097152 f32x4
        f32x4 v = ((const f32x4*)x)[i];
        u16x4 o;
        o[0] = f32_bf16(v[0]); o[1] = f32_bf16(v[1]);
        o[2] = f32_bf16(v[2]); o[3] = f32_bf16(v[3]);
        ((u16x4*)xb)[i] = o;
        return;
    }
    const float* in; unsigned short* out; int R, C, bx, by;
    if (blk < 11264) {
        int t = blk - 8192; in = caw; out = wqt; R = 1024; C = 3072;
        bx = t % 96; by = t / 96;
    } else {
        int t = blk - 11264; in = cpw; out = wpt; R = 1024; C = 1024;
        bx = t & 31; by = t >> 5;
    }
    int tx = tid & 31, ty = tid >> 5;
    int x0 = bx * 32, y0 = by * 32;
#pragma unroll
    for (int p = 0; p < 32; p += 8)
        tile[ty + p][tx] = in[(size_t)(y0 + ty + p) * C + x0 + tx];
    __syncthreads();
#pragma unroll
    for (int p = 0; p < 32; p += 8)
        out[(size_t)(x0 + ty + p) * R + y0 + tx] = f32_bf16(tile[tx][ty + p]);
}

// ---------------- shared 128x128 NT bf16 GEMM mainloop (BK=64) ----------------
// Single-buffered: 32 KB LDS -> 4 resident blocks/CU; R13 proved dbuf (64 KB,
// 2 blocks/CU) regresses -8% — cross-block wave overlap (m114) beats
// source-level pipelining at this tile size.
__device__ __forceinline__ void gemm128_mainloop(
    const unsigned short* __restrict__ A,
    const unsigned short* __restrict__ Bt,
    unsigned short* As, unsigned short* Bs,
    int m0, int n0, int Kdim, f32x4 acc[][4])
{
    const int tid = threadIdx.x;
    const int lane = tid & 63, wave = tid >> 6;
    const int wm = wave & 1, wn = wave >> 1;
    const int quad = lane >> 4, l15 = lane & 15;
    const int srow = wave * 8 + (lane >> 3);
    const int scol = ((lane & 7) ^ (lane >> 3)) * 8;   // swizzled chunk fetch
    const unsigned short* Ag = A + (size_t)(m0 + srow) * Kdim + scol;
    const unsigned short* Bg = Bt + (size_t)(n0 + srow) * Kdim + scol;
    unsigned short* Asw = As + (wave * 8) * 64 + lane * 8;
    unsigned short* Bsw = Bs + (wave * 8) * 64 + lane * 8;
    const int mkey = l15 & 7;

    for (int k0 = 0; k0 < Kdim; k0 += 64) {
        __syncthreads();
#pragma unroll
        for (int p = 0; p < 4; ++p)
            gload_lds16(Ag + (size_t)(p * 32) * Kdim + k0, Asw + (p * 32) * 64);
#pragma unroll
        for (int p = 0; p < 4; ++p)
            gload_lds16(Bg + (size_t)(p * 32) * Kdim + k0, Bsw + (p * 32) * 64);
        __syncthreads();
#pragma unroll
        for (int kh = 0; kh < 2; ++kh) {
            bf16x8 af[4], bfv[4];
#pragma unroll
            for (int i = 0; i < 4; ++i)
                af[i] = frag8(As + (wm * 64 + i * 16 + l15) * 64 +
                              ((((kh << 2) + quad) ^ mkey) << 3));
#pragma unroll
            for (int j = 0; j < 4; ++j)
                bfv[j] = frag8(Bs + (wn * 64 + j * 16 + l15) * 64 +
                               ((((kh << 2) + quad) ^ mkey) << 3));
#pragma unroll
            for (int i = 0; i < 4; ++i)
#pragma unroll
                for (int j = 0; j < 4; ++j)
                    acc[i][j] = __builtin_amdgcn_mfma_f32_16x16x32_bf16(
                        af[i], bfv[j], acc[i][j], 0, 0, 0);
        }
    }
}

// ---------------- QKV GEMM ----------------
// L2-aware intra-XCD ordering (R15): XCD x owns m-panels [8x,8x+8) as before,
// but iterates its 192 blocks in 3 n-groups of 8 panels (64 blocks each).
// Per-group working set = 2 MB A + 2 MB B = 4 MB = one XCD L2, and a group
// matches the per-XCD concurrency window (~64-74 blocks) -> B read once per
// group, A L2-resident across groups. Bijective remap, no resource change.
__global__ __launch_bounds__(256, 2) void gemm_qkv_k(
    const unsigned short* __restrict__ xb,
    const unsigned short* __restrict__ wt,
    const float* __restrict__ bias,
    unsigned short* __restrict__ q,
    unsigned short* __restrict__ k2,
    unsigned short* __restrict__ vt)
{
    __shared__ unsigned short Sh[128 * 132];   // mainloop uses first 32 KB
    unsigned short* As = Sh;
    unsigned short* Bs = Sh + 128 * 64;
    const int lin = blockIdx.x + 24 * blockIdx.y;        // grid 24x64 = 1536
    const int xcd = lin & 7;
    const int idx = lin >> 3;          // 0..191 within XCD (temporal order)
    const int g   = idx >> 6;          // n-group 0..2 (8 n-panels each)
    const int rem = idx & 63;
    const int mi  = rem >> 3;          // 0..7
    const int ni  = rem & 7;           // 0..7
    const int m0  = (xcd * 8 + mi) * 128;
    const int n0  = (g * 8 + ni) * 128;
    f32x4 acc[4][4] = {};
    gemm128_mainloop(xb, wt, As, Bs, m0, n0, 1024, acc);

    const int tid = threadIdx.x;
    const int lane = tid & 63, wave = tid >> 6;
    const int wm = wave & 1, wn = wave >> 1;
    const int quad = lane >> 4, l15 = lane & 15;
    const bool isq = (n0 < 1024);
    const bool isv = (n0 >= 2048);
    const int cb = n0 & 1023;

    if (!isv) {
        unsigned short* outp = isq ? q : k2;
#pragma unroll
        for (int j = 0; j < 4; ++j) {
            int ct = cb + wn * 64 + j * 16 + l15;
            int h = ct >> 6, d = ct & 63;
            float bv = bias[n0 + wn * 64 + j * 16 + l15];
#pragma unroll
            for (int i = 0; i < 4; ++i)
#pragma unroll
                for (int r = 0; r < 4; ++r) {
                    int row = m0 + wm * 64 + i * 16 + quad * 4 + r;
                    int bb = row >> 11, s = row & 2047;
                    float val = acc[i][j][r] + bv;
                    if (isq) val *= 0.1803368801111244f;   // (1/8)*log2(e)
                    outp[((size_t)(bb * 16 + h) * S_LEN + s) * HD + d] = f32_bf16(val);
                }
        }
    } else {
        // ---- V: write transposed [bh][d][s] via LDS (stride 132, bank-clean)
        __syncthreads();   // all waves done with As/Bs fragment reads
#pragma unroll
        for (int j = 0; j < 4; ++j) {
            float bv = bias[n0 + wn * 64 + j * 16 + l15];
            int lc = wn * 64 + j * 16 + l15;
#pragma unroll
            for (int i = 0; i < 4; ++i)
#pragma unroll
                for (int r = 0; r < 4; ++r) {
                    int lr = wm * 64 + i * 16 + quad * 4 + r;
                    Sh[lr * 132 + lc] = f32_bf16(acc[i][j][r] + bv);
                }
        }
        __syncthreads();
        const int lc = (tid & 63) + (wave & 1) * 64;     // 0..127
        const int sh2 = wave >> 1;                       // 0..1
        const int bb = m0 >> 11;
        const int s0 = (m0 & 2047) + sh2 * 64;
        const int bh = bb * 16 + (cb >> 6) + (lc >> 6);
        unsigned short* vp = vt + ((size_t)bh * HD + (lc & 63)) * S_LEN + s0;
#pragma unroll
        for (int k8 = 0; k8 < 8; ++k8) {
            u16x8 w;
#pragma unroll
            for (int e = 0; e < 8; ++e)
                w[e] = Sh[(sh2 * 64 + k8 * 8 + e) * 132 + lc];
            *(u16x8*)(vp + k8 * 8) = w;
        }
    }
}

// ---------------- proj GEMM -> f32 out ----------------
// Per-XCD working set already 2 MB A + 2 MB B = 4 MB (8 n-panels total) ->
// ordering is L2-clean as-is.
__global__ __launch_bounds__(256, 2) void gemm_proj_k(
    const unsigned short* __restrict__ am,
    const unsigned short* __restrict__ wpt,
    const float* __restrict__ bias,
    float* __restrict__ out)
{
    __shared__ unsigned short As[128 * 64], Bs[128 * 64];
    const int lin = blockIdx.x + 8 * blockIdx.y;         // grid 8x64 = 512
    const int swz = (lin & 7) * 64 + (lin >> 3);         // bijective chunked
    const int n0 = (swz % 8) * 128, m0 = (swz / 8) * 128;
    f32x4 acc[4][4] = {};
    gemm128_mainloop(am, wpt, As, Bs, m0, n0, 1024, acc);

    const int lane = threadIdx.x & 63, wave = threadIdx.x >> 6;
    const int wm = wave & 1, wn = wave >> 1;
    const int quad = lane >> 4, l15 = lane & 15;
#pragma unroll
    for (int j = 0; j < 4; ++j) {
        int col = n0 + wn * 64 + j * 16 + l15;
        float bv = bias[col];
#pragma unroll
        for (int i = 0; i < 4; ++i)
#pragma unroll
            for (int r = 0; r < 4; ++r) {
                int row = m0 + wm * 64 + i * 16 + quad * 4 + r;
                out[(size_t)row * 1024 + col] = acc[i][j][r] + bv;
            }
    }
}

// ---------------- flash attention v10: 1024 blocks, K+V staged, 3 blocks/CU --
// Best verified flash (R10: 60.4us, MfmaUtil 26%). One q-tile per block,
// 64bh x 16qt grid, qt-desc dispatch, bh-major XCD map, K/V dbuf via
// global_load_lds, setprio on MFMA, native RNE cvt, wave-0/1 masked-tile skip.
// R12 proved V-staging is load-bearing; R11 proved launch_bounds must stay
// (256,3) — forcing 4 waves/EU spills catastrophically.
#define PSTR 72
__global__ __launch_bounds__(256, 3) void flash_attn_k(
    const unsigned short* __restrict__ Q,
    const unsigned short* __restrict__ K,
    const unsigned short* __restrict__ Vt,
    unsigned short* __restrict__ Am)
{
    __shared__ unsigned short Ps[4 * 32 * PSTR];    // 18 KB
    __shared__ unsigned short Ks[2][64 * 64];       // 16 KB (dbuf)
    __shared__ unsigned short Vs[2][64 * 64];       // 16 KB (dbuf)

    const int bid = blockIdx.x;        // 1024 blocks
    const int xcd = bid & 7;
    const int w = bid >> 3;            // 0..127
    const int qt = 15 - (w >> 3);      // 15,15,..(x8),14,.. long-first
    const int bh = xcd * 8 + (w & 7);
    const int b = bh >> 4, h = bh & 15;
    const int tid = threadIdx.x;
    const int lane = tid & 63, wave = tid >> 6;
    const int quad = lane >> 4, l15 = lane & 15;

    const size_t bh_off = (size_t)bh * S_LEN * HD;
    const unsigned short* Kg = K + bh_off;
    const unsigned short* Vtg = Vt + (size_t)bh * HD * S_LEN;

    const int lrow = (lane >> 3) & 7;
    const int scol = ((lane & 7) ^ lrow) * 8;        // pre-swizzled source chunk
    const int srow = wave * 8 + lrow;
    const int ldst = (wave * 8) * 64 + lane * 8;     // linear LDS dest

    const int q_base = qt * 128 + wave * 32;

    // Q A-fragments, direct from global
    bf16x8 qa[2][2];
#pragma unroll
    for (int i = 0; i < 2; ++i)
#pragma unroll
        for (int kk = 0; kk < 2; ++kk)
            qa[i][kk] = frag8(Q + bh_off +
                (size_t)(q_base + i * 16 + l15) * HD + kk * 32 + quad * 8);

    f32x4 oacc[2][4] = {};
    f32x4 lacc[2] = {};
    u16x8 ones_u = {0x3F80, 0x3F80, 0x3F80, 0x3F80, 0x3F80, 0x3F80, 0x3F80, 0x3F80};
    bf16x8 vone = __builtin_bit_cast(bf16x8, ones_u);

    const int nst = 2 * qt + 2;              // uniform staging trip count
    const int nst_w = nst - ((wave < 2) ? 1 : 0);   // last tile fully masked
    unsigned short* pw = Ps + wave * (32 * PSTR);
    const int pkey = (l15 >> 2) & 3;
    const int kvkey = l15 & 7;

    // prologue: stage tile 0 into buffer 0
#pragma unroll
    for (int pp = 0; pp < 2; ++pp) {
        gload_lds16(Kg + (size_t)(srow + pp * 32) * HD + scol,
                    &Ks[0][ldst + (pp * 32) * 64]);
        gload_lds16(Vtg + (size_t)(srow + pp * 32) * S_LEN + scol,
                    &Vs[0][ldst + (pp * 32) * 64]);
    }
    __syncthreads();

    int cur = 0;
    for (int st = 0; st < nst; ++st) {
        if (st + 1 < nst) {
            const int nx = cur ^ 1;
            const size_t kroff = (size_t)((st + 1) * 64);
#pragma unroll
            for (int pp = 0; pp < 2; ++pp) {
                gload_lds16(Kg + (kroff + srow + pp * 32) * HD + scol,
                            &Ks[nx][ldst + (pp * 32) * 64]);
                gload_lds16(Vtg + (size_t)(srow + pp * 32) * S_LEN + kroff + scol,
                            &Vs[nx][ldst + (pp * 32) * 64]);
            }
        }
        const unsigned short* ksc = &Ks[cur][0];
        const unsigned short* vsc = &Vs[cur][0];

        if (st < nst_w) {
            // S' = (Q*scale) K^T, K fragments from LDS
            f32x4 sacc[2][4] = {};
            __builtin_amdgcn_s_setprio(1);
#pragma unroll
            for (int kk = 0; kk < 2; ++kk) {
                bf16x8 kb[4];
#pragma unroll
                for (int j = 0; j < 4; ++j)
                    kb[j] = frag8(ksc + (j * 16 + l15) * 64 +
                                  ((((kk << 2) + quad) ^ kvkey) << 3));
#pragma unroll
                for (int i = 0; i < 2; ++i)
#pragma unroll
                    for (int j = 0; j < 4; ++j)
                        sacc[i][j] = __builtin_amdgcn_mfma_f32_16x16x32_bf16(
                            qa[i][kk], kb[j], sacc[i][j], 0, 0, 0);
            }
            __builtin_amdgcn_s_setprio(0);

            // causal mask (diagonal-crossing tiles only)
            if (st * 64 + 63 > q_base) {
#pragma unroll
                for (int i = 0; i < 2; ++i)
#pragma unroll
                    for (int j = 0; j < 4; ++j)
#pragma unroll
                        for (int r = 0; r < 4; ++r) {
                            int kg = st * 64 + j * 16 + l15;
                            int qg = q_base + i * 16 + quad * 4 + r;
                            if (kg > qg) sacc[i][j][r] = -__builtin_inff();
                        }
            }

            // P = exp2(s') -> bf16 (native RNE, compiler-packed) -> LDS
#pragma unroll
            for (int i = 0; i < 2; ++i)
#pragma unroll
                for (int j = 0; j < 4; ++j) {
                    int cs = ((j ^ quad) << 4) + l15;
#pragma unroll
                    for (int r = 0; r < 4; ++r)
                        pw[(i * 16 + quad * 4 + r) * PSTR + cs] =
                            f32_bf16_rn(fast_exp2(sacc[i][j][r]));
                }

            // O += P @ V ; l += P @ 1   (V fragments from LDS, per-kk)
#pragma unroll
            for (int kk = 0; kk < 2; ++kk) {
                bf16x8 vb[4];
#pragma unroll
                for (int d4 = 0; d4 < 4; ++d4)
                    vb[d4] = frag8(vsc + (d4 * 16 + l15) * 64 +
                                   ((((kk << 2) + quad) ^ kvkey) << 3));
                const int coff = ((((kk << 1) + (quad >> 1)) ^ pkey) << 4) + ((quad & 1) << 3);

                bf16x8 pa[2];
#pragma unroll
                for (int i = 0; i < 2; ++i)
                    pa[i] = frag8(pw + (i * 16 + l15) * PSTR + coff);
                __builtin_amdgcn_s_setprio(1);
#pragma unroll
                for (int d4 = 0; d4 < 4; ++d4)
#pragma unroll
                    for (int i = 0; i < 2; ++i)
                        oacc[i][d4] = __builtin_amdgcn_mfma_f32_16x16x32_bf16(
                            pa[i], vb[d4], oacc[i][d4], 0, 0, 0);
#pragma unroll
                for (int i = 0; i < 2; ++i)
                    lacc[i] = __builtin_amdgcn_mfma_f32_16x16x32_bf16(
                        pa[i], vone, lacc[i], 0, 0, 0);
                __builtin_amdgcn_s_setprio(0);
            }
        }

        // handoff: all waves done reading buf[cur]; staging of buf[cur^1]
        // drained by the barrier's implicit vmcnt(0)
        __syncthreads();
        cur ^= 1;
    }

    // epilogue: O / l -> merged-head bf16 [B*S][1024]
    unsigned short* Amp = Am + ((size_t)(b * S_LEN + q_base)) * D_MODEL + h * 64;
#pragma unroll
    for (int i = 0; i < 2; ++i)
#pragma unroll
        for (int r = 0; r < 4; ++r) {
            float inv = 1.f / lacc[i][r];
            int qloc = i * 16 + quad * 4 + r;
#pragma unroll
            for (int d4 = 0; d4 < 4; ++d4)
                Amp[(size_t)qloc * D_MODEL + d4 * 16 + l15] =
                    f32_bf16_rn(oacc[i][d4][r] * inv);
        }
}

// ---------------- launcher ----------------
extern "C" void kernel_launch(void* const* d_in, const int* in_sizes, int n_in,
                              void* d_out, int out_size, void* d_ws, size_t ws_size,
                              hipStream_t stream)
{
    const float* x = (const float*)d_in[0];
    const float* c_attn_w = (const float*)d_in[1];
    const float* c_attn_b = (const float*)d_in[2];
    const float* c_proj_w = (const float*)d_in[3];
    const float* c_proj_b = (const float*)d_in[4];
    float* out = (float*)d_out;

    char* ws = (char*)d_ws;
    unsigned short* xb  = (unsigned short*)(ws);              // 16 MB; reused as Am
    unsigned short* q   = (unsigned short*)(ws + 16777216);   // 16 MB
    unsigned short* k   = (unsigned short*)(ws + 33554432);   // 16 MB
    unsigned short* vt  = (unsigned short*)(ws + 67108864);   // 16 MB
    unsigned short* wqt = (unsigned short*)(ws + 83886080);   // 6 MB
    unsigned short* wpt = (unsigned short*)(ws + 90177536);   // 2 MB

    prep_k<<<12288, 256, 0, stream>>>(x, xb, c_attn_w, wqt, c_proj_w, wpt);
    gemm_qkv_k<<<dim3(24, 64), 256, 0, stream>>>(xb, wqt, c_attn_b, q, k, vt);
    flash_attn_k<<<1024, 256, 0, stream>>>(q, k, vt, xb /*Am*/);
    gemm_proj_k<<<dim3(8, 64), 256, 0, stream>>>(xb /*Am*/, wpt, c_proj_b, out);
}